// Round 2
// baseline (5950.794 us; speedup 1.0000x reference)
//
#include <hip/hip_runtime.h>
#include <hip/hip_bf16.h>

#define EMBED 512
#define NHEAD 8
#define HDIM  64
#define B_    16
#define U_    1024
#define R_    256
#define S_    32
#define M_    31
#define Q_    (R_ + U_ + S_)   // 1312
#define KV_   (M_ + R_ + U_)   // 1311
#define NEG_INF_F (-100000000.0f)

// rows in flattened (len, B, EMBED) layouts
#define QROWS  (Q_ * B_)        // 20992
#define KVROWS (KV_ * B_)       // 20976
#define OROWS  (1311 * B_)      // 20976 (q row 1311 is dropped by the reference)
#define OUT0_ROWS (1280 * B_)   // 20480

// ---------------------------------------------------------------------------
// Generic projection GEMM: C[r][n] = sum_k A[r][k]*W[n][k] + bias[n]
// A rows are gathered from up to 3 concatenated sources.
// MODE 0: query proj  (scale 0.125 fused, write qs)
// MODE 1: kv proj     (split cols -> K, V)
// MODE 2: out proj    (contiguous src, split rows -> out0 / clipped out1)
// ---------------------------------------------------------------------------
template<int MODE>
__global__ __launch_bounds__(256) void proj_gemm(
    const float* __restrict__ s0, const float* __restrict__ s1, const float* __restrict__ s2,
    int n0, int n01, int nrows,
    const float* __restrict__ W, const float* __restrict__ bias,
    float scale,
    float* __restrict__ out0, float* __restrict__ out1)
{
    __shared__ float As[16][64];
    __shared__ float Ws[16][64];
    const int tid = threadIdx.x;
    const int lk  = tid & 15;   // k within k-tile (staging)
    const int lr  = tid >> 4;   // row group (staging)
    const int tx  = tid & 15;   // col group (compute)
    const int ty  = tid >> 4;   // row group (compute)
    const int row0 = blockIdx.x * 64;
    const int col0 = blockIdx.y * 64;

    const float* arow[4];
    #pragma unroll
    for (int i = 0; i < 4; ++i) {
        int r = row0 + lr + i * 16;
        if (r >= nrows)    { arow[i] = nullptr; }
        else if (MODE == 2){ arow[i] = s0 + (size_t)r * EMBED; }
        else if (r < n0)   { arow[i] = s0 + (size_t)r * EMBED; }
        else if (r < n01)  { arow[i] = s1 + (size_t)(r - n0) * EMBED; }
        else               { arow[i] = s2 + (size_t)(r - n01) * EMBED; }
    }

    float acc[4][4] = {};
    for (int k0 = 0; k0 < EMBED; k0 += 16) {
        __syncthreads();
        #pragma unroll
        for (int i = 0; i < 4; ++i) {
            As[lk][lr + i * 16] = arow[i] ? arow[i][k0 + lk] : 0.f;
            Ws[lk][lr + i * 16] = W[(size_t)(col0 + lr + i * 16) * EMBED + k0 + lk];
        }
        __syncthreads();
        #pragma unroll
        for (int kk = 0; kk < 16; ++kk) {
            float a[4], bb[4];
            #pragma unroll
            for (int i = 0; i < 4; ++i) a[i]  = As[kk][ty * 4 + i];
            #pragma unroll
            for (int j = 0; j < 4; ++j) bb[j] = Ws[kk][tx * 4 + j];
            #pragma unroll
            for (int i = 0; i < 4; ++i)
                #pragma unroll
                for (int j = 0; j < 4; ++j)
                    acc[i][j] += a[i] * bb[j];
        }
    }

    #pragma unroll
    for (int i = 0; i < 4; ++i) {
        int r = row0 + ty * 4 + i;
        if (r >= nrows) continue;
        #pragma unroll
        for (int j = 0; j < 4; ++j) {
            int c = col0 + tx * 4 + j;
            float v = (acc[i][j] + bias[c]) * scale;
            if (MODE == 0) {
                out0[(size_t)r * EMBED + c] = v;
            } else if (MODE == 1) {
                if (c < EMBED) out0[(size_t)r * EMBED + c] = v;
                else           out1[(size_t)r * EMBED + (c - EMBED)] = v;
            } else {
                if (r < OUT0_ROWS) out0[(size_t)r * EMBED + c] = v;
                else out1[(size_t)(r - OUT0_ROWS) * EMBED + c] = fminf(fmaxf(v, -10.f), 10.f);
            }
        }
    }
}

// ---------------------------------------------------------------------------
// Flash-style attention: one block = 32 q-rows of one (b,h). Online softmax.
// qs is pre-scaled by HDIM^-0.5. Masked scores are exactly NEG_INF (reference
// uses where(), so fully-masked rows give uniform softmax automatically).
// Masks are int32 (harness passes bool arrays as integer dtype).
// ---------------------------------------------------------------------------
__global__ __launch_bounds__(256) void attn_kernel(
    const float* __restrict__ Qs, const float* __restrict__ Kb, const float* __restrict__ Vb,
    const int* __restrict__ amask, const int* __restrict__ pmask,
    float* __restrict__ ctx)
{
    __shared__ __align__(16) float Qt[32][68];
    __shared__ __align__(16) float Kt[32][68];
    __shared__ __align__(16) float Vt[32][68];
    __shared__ float Sl[32][36];
    __shared__ float pmaxs[32][8];
    __shared__ float psums[32][8];
    __shared__ float mrow[32], srow[32], alph[32];

    const int tid = threadIdx.x;
    const int q0  = blockIdx.x * 32;
    const int bh  = blockIdx.y;
    const int b   = bh >> 3, h = bh & 7;

    for (int i = tid; i < 32 * 64; i += 256) {
        int r = i >> 6, d = i & 63;
        Qt[r][d] = Qs[((size_t)(q0 + r) * B_ + b) * EMBED + h * HDIM + d];
    }
    if (tid < 32) { mrow[tid] = -INFINITY; srow[tid] = 0.f; }

    const int sq = tid >> 3;       // q row owned (0..31)
    const int rr = tid & 7;        // sub-lane 0..7
    const int d0 = rr * 8;         // 8 output dims owned
    float O[8] = {0,0,0,0,0,0,0,0};

    for (int kt = 0; kt < 41; ++kt) {
        const int k0 = kt * 32;
        const int kn = (KV_ - k0) < 32 ? (KV_ - k0) : 32;
        __syncthreads();
        for (int i = tid; i < kn * 64; i += 256) {
            int r = i >> 6, d = i & 63;
            size_t base = ((size_t)(k0 + r) * B_ + b) * EMBED + h * HDIM + d;
            Kt[r][d] = Kb[base];
            Vt[r][d] = Vb[base];
        }
        __syncthreads();

        // --- scores: k = rr + 8j (strided to keep Kt reads on distinct banks)
        float accv[4] = {0.f, 0.f, 0.f, 0.f};
        {
            const float4* qrow = reinterpret_cast<const float4*>(&Qt[sq][0]);
            const float4* kr0 = reinterpret_cast<const float4*>(&Kt[rr      ][0]);
            const float4* kr1 = reinterpret_cast<const float4*>(&Kt[rr + 8  ][0]);
            const float4* kr2 = reinterpret_cast<const float4*>(&Kt[rr + 16 ][0]);
            const float4* kr3 = reinterpret_cast<const float4*>(&Kt[rr + 24 ][0]);
            #pragma unroll
            for (int dq = 0; dq < 16; ++dq) {
                float4 qv = qrow[dq];
                float4 k0v = kr0[dq], k1v = kr1[dq], k2v = kr2[dq], k3v = kr3[dq];
                accv[0] += qv.x*k0v.x + qv.y*k0v.y + qv.z*k0v.z + qv.w*k0v.w;
                accv[1] += qv.x*k1v.x + qv.y*k1v.y + qv.z*k1v.z + qv.w*k1v.w;
                accv[2] += qv.x*k2v.x + qv.y*k2v.y + qv.z*k2v.z + qv.w*k2v.w;
                accv[3] += qv.x*k3v.x + qv.y*k3v.y + qv.z*k3v.z + qv.w*k3v.w;
            }
        }
        float sv[4];
        float pm = -INFINITY;
        #pragma unroll
        for (int j = 0; j < 4; ++j) {
            int k = rr + 8 * j;
            float s = -INFINITY;
            if (k < kn) {
                int kg = k0 + k;
                bool masked = (amask[(size_t)(q0 + sq) * KV_ + kg] != 0) ||
                              (pmask[b * KV_ + kg] != 0);
                s = masked ? NEG_INF_F : accv[j];
            }
            sv[j] = s;
            pm = fmaxf(pm, s);
        }
        pmaxs[sq][rr] = pm;
        __syncthreads();
        if (tid < 32) {
            float mt = pmaxs[tid][0];
            #pragma unroll
            for (int j = 1; j < 8; ++j) mt = fmaxf(mt, pmaxs[tid][j]);
            float mn = fmaxf(mrow[tid], mt);
            alph[tid] = __expf(mrow[tid] - mn);
            mrow[tid] = mn;
        }
        __syncthreads();
        const float mn = mrow[sq];
        float ps = 0.f;
        #pragma unroll
        for (int j = 0; j < 4; ++j) {
            int k = rr + 8 * j;
            if (k < kn) {
                float p = __expf(sv[j] - mn);
                Sl[sq][k] = p;
                ps += p;
            }
        }
        psums[sq][rr] = ps;
        __syncthreads();
        if (tid < 32) {
            float t = 0.f;
            #pragma unroll
            for (int j = 0; j < 8; ++j) t += psums[tid][j];
            srow[tid] = srow[tid] * alph[tid] + t;
        }
        // --- PV (concurrent with srow update; arrays disjoint)
        const float al = alph[sq];
        #pragma unroll
        for (int j = 0; j < 8; ++j) O[j] *= al;
        for (int k = 0; k < kn; ++k) {
            float p = Sl[sq][k];
            const float4* vr = reinterpret_cast<const float4*>(&Vt[k][d0]);
            float4 v0 = vr[0], v1 = vr[1];
            O[0] += p * v0.x; O[1] += p * v0.y; O[2] += p * v0.z; O[3] += p * v0.w;
            O[4] += p * v1.x; O[5] += p * v1.y; O[6] += p * v1.z; O[7] += p * v1.w;
        }
    }
    __syncthreads();
    const float inv = 1.f / srow[sq];
    #pragma unroll
    for (int j = 0; j < 8; ++j)
        ctx[((size_t)(q0 + sq) * B_ + b) * EMBED + h * HDIM + d0 + j] = O[j] * inv;
}

// ---------------------------------------------------------------------------
extern "C" void kernel_launch(void* const* d_in, const int* in_sizes, int n_in,
                              void* d_out, int out_size, void* d_ws, size_t ws_size,
                              hipStream_t stream) {
    const float* utter = (const float*)d_in[0];
    const float* rctx  = (const float*)d_in[1];
    const float* summ  = (const float*)d_in[2];
    const float* mem   = (const float*)d_in[3];
    const int* amask   = (const int*)d_in[4];
    const int* pmask   = (const int*)d_in[5];
    const float* Wq  = (const float*)d_in[6];
    const float* bq  = (const float*)d_in[7];
    const float* Wkv = (const float*)d_in[8];
    const float* bkv = (const float*)d_in[9];
    const float* Wo  = (const float*)d_in[10];
    const float* bo  = (const float*)d_in[11];

    // workspace: qs | K | V | ctx  (~164 MB total, fp32)
    float* qs   = (float*)d_ws;
    float* Kbuf = qs   + (size_t)QROWS  * EMBED;
    float* Vbuf = Kbuf + (size_t)KVROWS * EMBED;
    float* ctx  = Vbuf + (size_t)KVROWS * EMBED;

    float* out0 = (float*)d_out;                       // (1280,16,512)
    float* out1 = out0 + (size_t)OUT0_ROWS * EMBED;    // (31,16,512)

    dim3 blk(256);

    // query projection (+bias, *0.125): q_in = [rc | utter | summ]
    proj_gemm<0><<<dim3((QROWS + 63) / 64, EMBED / 64), blk, 0, stream>>>(
        rctx, utter, summ, R_ * B_, (R_ + U_) * B_, QROWS,
        Wq, bq, 0.125f, qs, nullptr);

    // kv projection: kv_in = [mem | rc | utter], cols split into K / V
    proj_gemm<1><<<dim3((KVROWS + 63) / 64, (2 * EMBED) / 64), blk, 0, stream>>>(
        mem, rctx, utter, M_ * B_, (M_ + R_) * B_, KVROWS,
        Wkv, bkv, 1.0f, Kbuf, Vbuf);

    // attention
    attn_kernel<<<dim3(Q_ / 32, B_ * NHEAD), blk, 0, stream>>>(
        qs, Kbuf, Vbuf, amask, pmask, ctx);

    // output projection + split/clip epilogue (drops q row 1311)
    proj_gemm<2><<<dim3((OROWS + 63) / 64, EMBED / 64), blk, 0, stream>>>(
        ctx, nullptr, nullptr, OROWS, OROWS, OROWS,
        Wo, bo, 1.0f, out0, out1);
}

// Round 3
// 1592.050 us; speedup vs baseline: 3.7378x; 3.7378x over previous
//
#include <hip/hip_runtime.h>
#include <hip/hip_bf16.h>

#define EMBED 512
#define NHEAD 8
#define HDIM  64
#define B_    16
#define U_    1024
#define R_    256
#define S_    32
#define M_    31
#define Q_    (R_ + U_ + S_)   // 1312
#define KV_   (M_ + R_ + U_)   // 1311
#define NEG_INF_F (-100000000.0f)

#define QROWS  (Q_ * B_)        // 20992
#define KVROWS (KV_ * B_)       // 20976
#define OROWS  (1311 * B_)      // 20976
#define OUT0_ROWS (1280 * B_)   // 20480

typedef __attribute__((ext_vector_type(8))) short bf16x8;
typedef __attribute__((ext_vector_type(4))) float f32x4;
#define MFMA16(a, b, c) __builtin_amdgcn_mfma_f32_16x16x32_bf16(a, b, c, 0, 0, 0)

__device__ __forceinline__ unsigned short f2bf(float x) {
    unsigned u = __float_as_uint(x);
    u += 0x7fff + ((u >> 16) & 1);
    return (unsigned short)(u >> 16);
}
__device__ __forceinline__ float bf2f(unsigned short h) {
    return __uint_as_float((unsigned)h << 16);
}

// ---------------------------------------------------------------------------
// Projection GEMM (unchanged from round 2 — fp32 VALU; MFMA port next round)
// ---------------------------------------------------------------------------
template<int MODE>
__global__ __launch_bounds__(256) void proj_gemm(
    const float* __restrict__ s0, const float* __restrict__ s1, const float* __restrict__ s2,
    int n0, int n01, int nrows,
    const float* __restrict__ W, const float* __restrict__ bias,
    float scale,
    float* __restrict__ out0, float* __restrict__ out1)
{
    __shared__ float As[16][64];
    __shared__ float Ws[16][64];
    const int tid = threadIdx.x;
    const int lk  = tid & 15;
    const int lr  = tid >> 4;
    const int tx  = tid & 15;
    const int ty  = tid >> 4;
    const int row0 = blockIdx.x * 64;
    const int col0 = blockIdx.y * 64;

    const float* arow[4];
    #pragma unroll
    for (int i = 0; i < 4; ++i) {
        int r = row0 + lr + i * 16;
        if (r >= nrows)    { arow[i] = nullptr; }
        else if (MODE == 2){ arow[i] = s0 + (size_t)r * EMBED; }
        else if (r < n0)   { arow[i] = s0 + (size_t)r * EMBED; }
        else if (r < n01)  { arow[i] = s1 + (size_t)(r - n0) * EMBED; }
        else               { arow[i] = s2 + (size_t)(r - n01) * EMBED; }
    }

    float acc[4][4] = {};
    for (int k0 = 0; k0 < EMBED; k0 += 16) {
        __syncthreads();
        #pragma unroll
        for (int i = 0; i < 4; ++i) {
            As[lk][lr + i * 16] = arow[i] ? arow[i][k0 + lk] : 0.f;
            Ws[lk][lr + i * 16] = W[(size_t)(col0 + lr + i * 16) * EMBED + k0 + lk];
        }
        __syncthreads();
        #pragma unroll
        for (int kk = 0; kk < 16; ++kk) {
            float a[4], bb[4];
            #pragma unroll
            for (int i = 0; i < 4; ++i) a[i]  = As[kk][ty * 4 + i];
            #pragma unroll
            for (int j = 0; j < 4; ++j) bb[j] = Ws[kk][tx * 4 + j];
            #pragma unroll
            for (int i = 0; i < 4; ++i)
                #pragma unroll
                for (int j = 0; j < 4; ++j)
                    acc[i][j] += a[i] * bb[j];
        }
    }

    #pragma unroll
    for (int i = 0; i < 4; ++i) {
        int r = row0 + ty * 4 + i;
        if (r >= nrows) continue;
        #pragma unroll
        for (int j = 0; j < 4; ++j) {
            int c = col0 + tx * 4 + j;
            float v = (acc[i][j] + bias[c]) * scale;
            if (MODE == 0) {
                out0[(size_t)r * EMBED + c] = v;
            } else if (MODE == 1) {
                if (c < EMBED) out0[(size_t)r * EMBED + c] = v;
                else           out1[(size_t)r * EMBED + (c - EMBED)] = v;
            } else {
                if (r < OUT0_ROWS) out0[(size_t)r * EMBED + c] = v;
                else out1[(size_t)(r - OUT0_ROWS) * EMBED + c] = fminf(fmaxf(v, -10.f), 10.f);
            }
        }
    }
}

// ---------------------------------------------------------------------------
// MFMA flash attention. Block = 4 waves; wave w owns q rows q0+w*16..+15.
// K split hi/lo bf16 in LDS (3-term QK^T ~= fp32); V transposed in LDS.
// Softmax online, in D-layout, via 16-lane shfl reductions.
// Fragment maps (mfma_f32_16x16x32_bf16):
//   A: row=l&15,  k=(l>>4)*8+j   B: col=l&15, k=(l>>4)*8+j
//   D: col=l&15, row=(l>>4)*4+r
// ---------------------------------------------------------------------------
__global__ __launch_bounds__(256) void attn_mfma(
    const float* __restrict__ Qs, const float* __restrict__ Kb, const float* __restrict__ Vb,
    const int* __restrict__ amask, const int* __restrict__ pmask,
    float* __restrict__ ctx)
{
    __shared__ __align__(16) unsigned short Khi[32][64];   // XOR-swizzled 16B granules
    __shared__ __align__(16) unsigned short Klo[32][64];
    __shared__ __align__(16) unsigned short Vt[64][40];    // V transposed, pad->40
    __shared__ __align__(16) unsigned short Pb[4][16][40]; // per-wave P, pad->40

    const int tid = threadIdx.x;
    const int w   = tid >> 6;
    const int l   = tid & 63;
    const int l15 = l & 15;
    const int l4  = l >> 4;
    const int q0  = blockIdx.x * 64;
    const int bh  = blockIdx.y;
    const int b   = bh >> 3, h = bh & 7;

    // --- Q fragments (A operand), hi/lo split, per d-half
    bf16x8 Qhi[2], Qlo[2];
    {
        int qa = q0 + w * 16 + l15;
        int qac = qa < Q_ ? qa : 0;
        #pragma unroll
        for (int dh = 0; dh < 2; ++dh) {
            const float* p = Qs + ((size_t)qac * B_ + b) * EMBED + h * HDIM + dh * 32 + l4 * 8;
            float4 x0 = *(const float4*)p;
            float4 x1 = *(const float4*)(p + 4);
            float xs[8] = {x0.x, x0.y, x0.z, x0.w, x1.x, x1.y, x1.z, x1.w};
            bf16x8 hv, lv;
            #pragma unroll
            for (int j = 0; j < 8; ++j) {
                unsigned short hb = f2bf(xs[j]);
                hv[j] = (short)hb;
                lv[j] = (short)f2bf(xs[j] - bf2f(hb));
            }
            Qhi[dh] = hv; Qlo[dh] = lv;
        }
    }

    float m[4]    = {-INFINITY, -INFINITY, -INFINITY, -INFINITY};
    float ssum[4] = {0.f, 0.f, 0.f, 0.f};
    f32x4 O[4];
    #pragma unroll
    for (int dg = 0; dg < 4; ++dg) O[dg] = (f32x4){0.f, 0.f, 0.f, 0.f};

    const int sk = tid >> 3;       // staging k row (0..31)
    const int sg = tid & 7;        // staging granule (0..7)

    for (int kt = 0; kt < 41; ++kt) {
        const int k0 = kt * 32;
        const int kn = (KV_ - k0) < 32 ? (KV_ - k0) : 32;
        __syncthreads();

        // --- stage K hi/lo (XOR-swizzled granules)
        {
            bf16x8 hv, lv;
            if (sk < kn) {
                const float* kp = Kb + ((size_t)(k0 + sk) * B_ + b) * EMBED + h * HDIM + sg * 8;
                float4 x0 = *(const float4*)kp;
                float4 x1 = *(const float4*)(kp + 4);
                float xs[8] = {x0.x, x0.y, x0.z, x0.w, x1.x, x1.y, x1.z, x1.w};
                #pragma unroll
                for (int j = 0; j < 8; ++j) {
                    unsigned short hb = f2bf(xs[j]);
                    hv[j] = (short)hb;
                    lv[j] = (short)f2bf(xs[j] - bf2f(hb));
                }
            } else {
                #pragma unroll
                for (int j = 0; j < 8; ++j) { hv[j] = 0; lv[j] = 0; }
            }
            int g2 = sg ^ (sk & 7);
            *reinterpret_cast<bf16x8*>(&Khi[sk][g2 * 8]) = hv;
            *reinterpret_cast<bf16x8*>(&Klo[sk][g2 * 8]) = lv;
        }
        // --- stage V transposed: thread covers d = sg + 8j (bank-spread writes)
        {
            const float* vp = Vb + ((size_t)(k0 + (sk < kn ? sk : 0)) * B_ + b) * EMBED + h * HDIM;
            #pragma unroll
            for (int j = 0; j < 8; ++j) {
                int d = sg + 8 * j;
                float v = (sk < kn) ? vp[d] : 0.f;
                Vt[d][sk] = f2bf(v);
            }
        }
        __syncthreads();

        // --- QK^T: S[c] = Qhi.Khi + Qhi.Klo + Qlo.Khi  (c = k-col half)
        f32x4 S[2];
        #pragma unroll
        for (int c = 0; c < 2; ++c) {
            f32x4 acc = (f32x4){0.f, 0.f, 0.f, 0.f};
            int krow = c * 16 + l15;
            #pragma unroll
            for (int dh = 0; dh < 2; ++dh) {
                int gr = (dh * 4 + l4) ^ (krow & 7);
                bf16x8 Bh = *reinterpret_cast<const bf16x8*>(&Khi[krow][gr * 8]);
                bf16x8 Bl = *reinterpret_cast<const bf16x8*>(&Klo[krow][gr * 8]);
                acc = MFMA16(Qhi[dh], Bh, acc);
                acc = MFMA16(Qlo[dh], Bh, acc);
                acc = MFMA16(Qhi[dh], Bl, acc);
            }
            S[c] = acc;
        }

        // --- masks + online softmax (rows = l4*4+r, cols = c*16+l15)
        const int kg0 = k0 + l15;
        const int kg1 = k0 + 16 + l15;
        const int pm0 = (kg0 < KV_) ? pmask[b * KV_ + kg0] : 1;
        const int pm1 = (kg1 < KV_) ? pmask[b * KV_ + kg1] : 1;

        float sv0[4], sv1[4], al[4];
        #pragma unroll
        for (int r = 0; r < 4; ++r) {
            int qd = q0 + w * 16 + l4 * 4 + r;
            const int* arow = amask + (size_t)(qd < Q_ ? qd : 0) * KV_;
            float s0 = S[0][r], s1 = S[1][r];
            if (kg0 >= KV_) s0 = -INFINITY; else if (pm0 || arow[kg0]) s0 = NEG_INF_F;
            if (kg1 >= KV_) s1 = -INFINITY; else if (pm1 || arow[kg1]) s1 = NEG_INF_F;
            sv0[r] = s0; sv1[r] = s1;
        }
        #pragma unroll
        for (int r = 0; r < 4; ++r) {
            float t = fmaxf(sv0[r], sv1[r]);
            #pragma unroll
            for (int msk = 1; msk < 16; msk <<= 1) t = fmaxf(t, __shfl_xor(t, msk, 64));
            float mn = fmaxf(m[r], t);
            al[r] = __expf(m[r] - mn);
            m[r] = mn;
            float p0 = __expf(sv0[r] - mn);
            float p1 = __expf(sv1[r] - mn);
            sv0[r] = p0; sv1[r] = p1;
            float ps = p0 + p1;
            #pragma unroll
            for (int msk = 1; msk < 16; msk <<= 1) ps += __shfl_xor(ps, msk, 64);
            ssum[r] = ssum[r] * al[r] + ps;
        }
        // --- write P (bf16) to per-wave buffer
        #pragma unroll
        for (int r = 0; r < 4; ++r) {
            int qr = l4 * 4 + r;
            Pb[w][qr][l15]      = f2bf(sv0[r]);
            Pb[w][qr][16 + l15] = f2bf(sv1[r]);
        }
        // --- rescale O, then PV  (DS ops per-wave are in-order: write->read safe)
        #pragma unroll
        for (int dg = 0; dg < 4; ++dg) {
            #pragma unroll
            for (int r = 0; r < 4; ++r) O[dg][r] *= al[r];
        }
        bf16x8 PA = *reinterpret_cast<const bf16x8*>(&Pb[w][l15][l4 * 8]);
        #pragma unroll
        for (int dg = 0; dg < 4; ++dg) {
            bf16x8 VB = *reinterpret_cast<const bf16x8*>(&Vt[dg * 16 + l15][l4 * 8]);
            O[dg] = MFMA16(PA, VB, O[dg]);
        }
    }

    // --- epilogue
    #pragma unroll
    for (int r = 0; r < 4; ++r) {
        int qd = q0 + w * 16 + l4 * 4 + r;
        if (qd >= Q_) continue;
        float inv = 1.f / ssum[r];
        #pragma unroll
        for (int dg = 0; dg < 4; ++dg)
            ctx[((size_t)qd * B_ + b) * EMBED + h * HDIM + dg * 16 + l15] = O[dg][r] * inv;
    }
}

// ---------------------------------------------------------------------------
extern "C" void kernel_launch(void* const* d_in, const int* in_sizes, int n_in,
                              void* d_out, int out_size, void* d_ws, size_t ws_size,
                              hipStream_t stream) {
    const float* utter = (const float*)d_in[0];
    const float* rctx  = (const float*)d_in[1];
    const float* summ  = (const float*)d_in[2];
    const float* mem   = (const float*)d_in[3];
    const int* amask   = (const int*)d_in[4];
    const int* pmask   = (const int*)d_in[5];
    const float* Wq  = (const float*)d_in[6];
    const float* bq  = (const float*)d_in[7];
    const float* Wkv = (const float*)d_in[8];
    const float* bkv = (const float*)d_in[9];
    const float* Wo  = (const float*)d_in[10];
    const float* bo  = (const float*)d_in[11];

    float* qs   = (float*)d_ws;
    float* Kbuf = qs   + (size_t)QROWS  * EMBED;
    float* Vbuf = Kbuf + (size_t)KVROWS * EMBED;
    float* ctx  = Vbuf + (size_t)KVROWS * EMBED;

    float* out0 = (float*)d_out;
    float* out1 = out0 + (size_t)OUT0_ROWS * EMBED;

    dim3 blk(256);

    proj_gemm<0><<<dim3((QROWS + 63) / 64, EMBED / 64), blk, 0, stream>>>(
        rctx, utter, summ, R_ * B_, (R_ + U_) * B_, QROWS,
        Wq, bq, 0.125f, qs, nullptr);

    proj_gemm<1><<<dim3((KVROWS + 63) / 64, (2 * EMBED) / 64), blk, 0, stream>>>(
        mem, rctx, utter, M_ * B_, (M_ + R_) * B_, KVROWS,
        Wkv, bkv, 1.0f, Kbuf, Vbuf);

    attn_mfma<<<dim3((Q_ + 63) / 64, B_ * NHEAD), blk, 0, stream>>>(
        qs, Kbuf, Vbuf, amask, pmask, ctx);

    proj_gemm<2><<<dim3((OROWS + 63) / 64, EMBED / 64), blk, 0, stream>>>(
        ctx, nullptr, nullptr, OROWS, OROWS, OROWS,
        Wo, bo, 1.0f, out0, out1);
}

// Round 4
// 809.394 us; speedup vs baseline: 7.3522x; 1.9670x over previous
//
#include <hip/hip_runtime.h>
#include <hip/hip_bf16.h>

#define EMBED 512
#define NHEAD 8
#define HDIM  64
#define B_    16
#define U_    1024
#define R_    256
#define S_    32
#define M_    31
#define Q_    (R_ + U_ + S_)   // 1312
#define KV_   (M_ + R_ + U_)   // 1311
#define NEG_INF_F (-100000000.0f)

#define QROWS  (Q_ * B_)        // 20992
#define KVROWS (KV_ * B_)       // 20976
#define OROWS  (1311 * B_)      // 20976
#define OUT0_ROWS (1280 * B_)   // 20480

typedef __attribute__((ext_vector_type(8))) short bf16x8;
typedef __attribute__((ext_vector_type(4))) float f32x4;
#define MFMA16(a, b, c) __builtin_amdgcn_mfma_f32_16x16x32_bf16(a, b, c, 0, 0, 0)

typedef unsigned short ushort_t;

__device__ __forceinline__ unsigned short f2bf(float x) {
    unsigned u = __float_as_uint(x);
    u += 0x7fff + ((u >> 16) & 1);
    return (unsigned short)(u >> 16);
}
__device__ __forceinline__ float bf2f(unsigned short h) {
    return __uint_as_float((unsigned)h << 16);
}

__device__ __forceinline__ void gload_lds16(const void* g, void* l) {
    __builtin_amdgcn_global_load_lds(
        (const __attribute__((address_space(1))) unsigned int*)g,
        (__attribute__((address_space(3))) unsigned int*)l, 16, 0, 0);
}

// ---------------------------------------------------------------------------
// fp32 -> hi/lo bf16 split (8 elements / thread)
// ---------------------------------------------------------------------------
__global__ __launch_bounds__(256) void cvt_hilo(
    const float* __restrict__ src, ushort_t* __restrict__ hi,
    ushort_t* __restrict__ lo, int n8)
{
    int i = blockIdx.x * 256 + threadIdx.x;
    if (i >= n8) return;
    const float4* s = (const float4*)(src + (size_t)i * 8);
    float4 a = s[0], b2 = s[1];
    float xs[8] = {a.x, a.y, a.z, a.w, b2.x, b2.y, b2.z, b2.w};
    bf16x8 hv, lv;
    #pragma unroll
    for (int j = 0; j < 8; ++j) {
        unsigned short hb = f2bf(xs[j]);
        hv[j] = (short)hb;
        lv[j] = (short)f2bf(xs[j] - bf2f(hb));
    }
    *(bf16x8*)(hi + (size_t)i * 8) = hv;
    *(bf16x8*)(lo + (size_t)i * 8) = lv;
}

// ---------------------------------------------------------------------------
// MFMA projection GEMM, hi/lo split operands (fp32-accurate: 3-term).
// C[r][n] = sum_k A[r][k]*W[n][k] + bias[n]   (then *scale)
// 128x128 tile, BK=64, 4 waves (2x2 of 64x64). global_load_lds staging with
// pre-swizzled source granule (g ^= row&7); swizzled ds_read_b128 on read.
// MODE 0: out = q hi/lo planes. MODE 1: cols<512 -> K hi/lo, else V bf16.
// MODE 2: fp32 out0 / clipped out1, row split.
// ---------------------------------------------------------------------------
template<int MODE>
__global__ __launch_bounds__(256) void gemm_mfma(
    const ushort_t* __restrict__ Ahi, const ushort_t* __restrict__ Alo,
    const ushort_t* __restrict__ Whi, const ushort_t* __restrict__ Wlo,
    const float* __restrict__ bias, float scale,
    int n0, int n01, int nrows,
    size_t off0, size_t off1, size_t off2,
    void* __restrict__ o0, void* __restrict__ o1, void* __restrict__ o2)
{
    __shared__ __align__(16) ushort_t lAhi[128][64];
    __shared__ __align__(16) ushort_t lAlo[128][64];
    __shared__ __align__(16) ushort_t lWhi[128][64];
    __shared__ __align__(16) ushort_t lWlo[128][64];

    const int tid = threadIdx.x;
    const int w   = tid >> 6;
    const int l   = tid & 63;
    const int l15 = l & 15;
    const int l4  = l >> 4;
    const int row0 = blockIdx.x * 128;
    const int col0 = blockIdx.y * 128;

    // staging source pointers (per-lane, gather + swizzled granule)
    const int drow = l >> 3;               // row within 8-row chunk
    const int sgr  = (l & 7) ^ drow;       // pre-swizzled source granule
    const ushort_t* aptr[4];
    const ushort_t* wptr[4];
    #pragma unroll
    for (int c = 0; c < 4; ++c) {
        int r = row0 + w * 32 + c * 8 + drow;
        int rc = r < nrows ? r : nrows - 1;
        size_t roff;
        if (MODE == 2)      roff = (size_t)rc * EMBED;
        else if (rc < n0)   roff = off0 + (size_t)rc * EMBED;
        else if (rc < n01)  roff = off1 + (size_t)(rc - n0) * EMBED;
        else                roff = off2 + (size_t)(rc - n01) * EMBED;
        aptr[c] = Ahi + roff + sgr * 8;
        int wr = col0 + w * 32 + c * 8 + drow;
        wptr[c] = Whi + (size_t)wr * EMBED + sgr * 8;
    }
    const ptrdiff_t dA = Alo - Ahi;   // same ws allocation: well-defined
    const ptrdiff_t dW = Wlo - Whi;

    f32x4 acc[4][4];
    #pragma unroll
    for (int mi = 0; mi < 4; ++mi)
        #pragma unroll
        for (int nj = 0; nj < 4; ++nj) acc[mi][nj] = (f32x4){0.f, 0.f, 0.f, 0.f};

    const int wrow = (w >> 1) * 64;
    const int wcol = (w & 1) * 64;

    for (int t = 0; t < 8; ++t) {
        __syncthreads();
        const int ke = t * 64;
        #pragma unroll
        for (int c = 0; c < 4; ++c) {
            gload_lds16(aptr[c] + ke,      &lAhi[w * 32 + c * 8][0]);
            gload_lds16(aptr[c] + ke + dA, &lAlo[w * 32 + c * 8][0]);
            gload_lds16(wptr[c] + ke,      &lWhi[w * 32 + c * 8][0]);
            gload_lds16(wptr[c] + ke + dW, &lWlo[w * 32 + c * 8][0]);
        }
        __syncthreads();

        #pragma unroll
        for (int kk = 0; kk < 2; ++kk) {
            bf16x8 ah[4], al_[4], wh[4], wl[4];
            #pragma unroll
            for (int mi = 0; mi < 4; ++mi) {
                int row = wrow + mi * 16 + l15;
                int g = (((kk * 4 + l4) ^ (l15 & 7))) * 8;
                ah[mi]  = *(const bf16x8*)&lAhi[row][g];
                al_[mi] = *(const bf16x8*)&lAlo[row][g];
            }
            #pragma unroll
            for (int nj = 0; nj < 4; ++nj) {
                int row = wcol + nj * 16 + l15;
                int g = (((kk * 4 + l4) ^ (l15 & 7))) * 8;
                wh[nj] = *(const bf16x8*)&lWhi[row][g];
                wl[nj] = *(const bf16x8*)&lWlo[row][g];
            }
            #pragma unroll
            for (int mi = 0; mi < 4; ++mi)
                #pragma unroll
                for (int nj = 0; nj < 4; ++nj) {
                    acc[mi][nj] = MFMA16(ah[mi],  wh[nj], acc[mi][nj]);
                    acc[mi][nj] = MFMA16(al_[mi], wh[nj], acc[mi][nj]);
                    acc[mi][nj] = MFMA16(ah[mi],  wl[nj], acc[mi][nj]);
                }
        }
    }

    // epilogue: D layout col=l15, row=l4*4+r
    #pragma unroll
    for (int nj = 0; nj < 4; ++nj) {
        int gc = col0 + wcol + nj * 16 + l15;
        float bv = bias[gc];
        #pragma unroll
        for (int mi = 0; mi < 4; ++mi) {
            #pragma unroll
            for (int r = 0; r < 4; ++r) {
                int gr = row0 + wrow + mi * 16 + l4 * 4 + r;
                if (gr >= nrows) continue;
                float v = (acc[mi][nj][r] + bv) * scale;
                if (MODE == 0) {
                    unsigned short hb = f2bf(v);
                    ((ushort_t*)o0)[(size_t)gr * EMBED + gc] = hb;
                    ((ushort_t*)o1)[(size_t)gr * EMBED + gc] = f2bf(v - bf2f(hb));
                } else if (MODE == 1) {
                    if (gc < EMBED) {
                        unsigned short hb = f2bf(v);
                        ((ushort_t*)o0)[(size_t)gr * EMBED + gc] = hb;
                        ((ushort_t*)o1)[(size_t)gr * EMBED + gc] = f2bf(v - bf2f(hb));
                    } else {
                        ((ushort_t*)o2)[(size_t)gr * EMBED + (gc - EMBED)] = f2bf(v);
                    }
                } else {
                    if (gr < OUT0_ROWS)
                        ((float*)o0)[(size_t)gr * EMBED + gc] = v;
                    else if (gr < OROWS)
                        ((float*)o1)[(size_t)(gr - OUT0_ROWS) * EMBED + gc] =
                            fminf(fmaxf(v, -10.f), 10.f);
                }
            }
        }
    }
}

// ---------------------------------------------------------------------------
// MFMA flash attention. Reads pre-split Q/K hi-lo planes and V bf16 plane.
// K staged via global_load_lds (swizzle involution g^=(row&7) on source &
// read). V reg-staged transposed with j-rotation to spread banks.
// Writes ctx as hi/lo bf16 planes for the MFMA out-projection.
// ---------------------------------------------------------------------------
__global__ __launch_bounds__(256) void attn_mfma(
    const ushort_t* __restrict__ Qhi_p, const ushort_t* __restrict__ Qlo_p,
    const ushort_t* __restrict__ Khi_p, const ushort_t* __restrict__ Klo_p,
    const ushort_t* __restrict__ Vp,
    const int* __restrict__ amask, const int* __restrict__ pmask,
    ushort_t* __restrict__ Chi_p, ushort_t* __restrict__ Clo_p)
{
    __shared__ __align__(16) ushort_t Khi[32][64];
    __shared__ __align__(16) ushort_t Klo[32][64];
    __shared__ __align__(16) ushort_t Vt[64][40];
    __shared__ __align__(16) ushort_t Pb[4][16][40];

    const int tid = threadIdx.x;
    const int w   = tid >> 6;
    const int l   = tid & 63;
    const int l15 = l & 15;
    const int l4  = l >> 4;
    const int q0  = blockIdx.x * 64;
    const int bh  = blockIdx.y;
    const int b   = bh >> 3, h = bh & 7;

    // --- Q fragments from pre-split planes
    bf16x8 Qhi[2], Qlo[2];
    {
        int qa = q0 + w * 16 + l15;
        if (qa >= Q_) qa = Q_ - 1;
        size_t base = ((size_t)qa * B_ + b) * EMBED + h * HDIM;
        #pragma unroll
        for (int dh = 0; dh < 2; ++dh) {
            Qhi[dh] = *(const bf16x8*)(Qhi_p + base + dh * 32 + l4 * 8);
            Qlo[dh] = *(const bf16x8*)(Qlo_p + base + dh * 32 + l4 * 8);
        }
    }

    float m[4]    = {-INFINITY, -INFINITY, -INFINITY, -INFINITY};
    float ssum[4] = {0.f, 0.f, 0.f, 0.f};
    f32x4 O[4];
    #pragma unroll
    for (int dg = 0; dg < 4; ++dg) O[dg] = (f32x4){0.f, 0.f, 0.f, 0.f};

    const int sk = tid >> 3;       // V staging k row (0..31)
    const int sg = tid & 7;        // V staging granule
    // K staging (gload_lds): wave w covers tile rows w*8..w*8+7
    const int krl = w * 8 + (l >> 3);          // my tile row
    const int ksg = (l & 7) ^ (l >> 3);        // pre-swizzled source granule

    for (int kt = 0; kt < 41; ++kt) {
        const int k0 = kt * 32;
        const int kn = (KV_ - k0) < 32 ? (KV_ - k0) : 32;
        __syncthreads();

        // --- K tiles via global_load_lds (1KB per wave per plane)
        {
            int kv = k0 + krl;
            if (kv >= KV_) kv = KV_ - 1;
            size_t base = ((size_t)kv * B_ + b) * EMBED + h * HDIM + ksg * 8;
            gload_lds16(Khi_p + base, &Khi[w * 8][0]);
            gload_lds16(Klo_p + base, &Klo[w * 8][0]);
        }
        // --- V transposed (reg-staged, j-rotated writes)
        {
            int kv = k0 + sk;
            if (kv >= KV_) kv = KV_ - 1;
            bf16x8 vv;
            if (sk < kn) {
                vv = *(const bf16x8*)(Vp + ((size_t)kv * B_ + b) * EMBED + h * HDIM + sg * 8);
            } else {
                #pragma unroll
                for (int j = 0; j < 8; ++j) vv[j] = 0;
            }
            #pragma unroll
            for (int j = 0; j < 8; ++j) {
                int jj = (j + sg) & 7;
                Vt[sg * 8 + jj][sk] = (ushort_t)vv[jj];
            }
        }
        __syncthreads();

        // --- QK^T (3-term hi/lo)
        f32x4 S[2];
        #pragma unroll
        for (int c = 0; c < 2; ++c) {
            f32x4 acc = (f32x4){0.f, 0.f, 0.f, 0.f};
            int krow = c * 16 + l15;
            #pragma unroll
            for (int dh = 0; dh < 2; ++dh) {
                int gr = ((dh * 4 + l4) ^ (krow & 7)) * 8;
                bf16x8 Bh = *(const bf16x8*)&Khi[krow][gr];
                bf16x8 Bl = *(const bf16x8*)&Klo[krow][gr];
                acc = MFMA16(Qhi[dh], Bh, acc);
                acc = MFMA16(Qlo[dh], Bh, acc);
                acc = MFMA16(Qhi[dh], Bl, acc);
            }
            S[c] = acc;
        }

        // --- masks + online softmax
        const int kg0 = k0 + l15;
        const int kg1 = k0 + 16 + l15;
        const int pm0 = (kg0 < KV_) ? pmask[b * KV_ + kg0] : 1;
        const int pm1 = (kg1 < KV_) ? pmask[b * KV_ + kg1] : 1;

        float sv0[4], sv1[4], al[4];
        #pragma unroll
        for (int r = 0; r < 4; ++r) {
            int qd = q0 + w * 16 + l4 * 4 + r;
            const int* arow = amask + (size_t)(qd < Q_ ? qd : 0) * KV_;
            float s0 = S[0][r], s1 = S[1][r];
            if (kg0 >= KV_) s0 = -INFINITY; else if (pm0 || arow[kg0]) s0 = NEG_INF_F;
            if (kg1 >= KV_) s1 = -INFINITY; else if (pm1 || arow[kg1]) s1 = NEG_INF_F;
            sv0[r] = s0; sv1[r] = s1;
        }
        #pragma unroll
        for (int r = 0; r < 4; ++r) {
            float t = fmaxf(sv0[r], sv1[r]);
            #pragma unroll
            for (int msk = 1; msk < 16; msk <<= 1) t = fmaxf(t, __shfl_xor(t, msk, 64));
            float mn = fmaxf(m[r], t);
            al[r] = __expf(m[r] - mn);
            m[r] = mn;
            float p0 = __expf(sv0[r] - mn);
            float p1 = __expf(sv1[r] - mn);
            sv0[r] = p0; sv1[r] = p1;
            float ps = p0 + p1;
            #pragma unroll
            for (int msk = 1; msk < 16; msk <<= 1) ps += __shfl_xor(ps, msk, 64);
            ssum[r] = ssum[r] * al[r] + ps;
        }
        #pragma unroll
        for (int r = 0; r < 4; ++r) {
            int qr = l4 * 4 + r;
            Pb[w][qr][l15]      = f2bf(sv0[r]);
            Pb[w][qr][16 + l15] = f2bf(sv1[r]);
        }
        #pragma unroll
        for (int dg = 0; dg < 4; ++dg) {
            #pragma unroll
            for (int r = 0; r < 4; ++r) O[dg][r] *= al[r];
        }
        bf16x8 PA = *(const bf16x8*)&Pb[w][l15][l4 * 8];
        #pragma unroll
        for (int dg = 0; dg < 4; ++dg) {
            bf16x8 VB = *(const bf16x8*)&Vt[dg * 16 + l15][l4 * 8];
            O[dg] = MFMA16(PA, VB, O[dg]);
        }
    }

    // --- epilogue: write ctx hi/lo planes
    #pragma unroll
    for (int r = 0; r < 4; ++r) {
        int qd = q0 + w * 16 + l4 * 4 + r;
        if (qd >= Q_) continue;
        float inv = 1.f / ssum[r];
        #pragma unroll
        for (int dg = 0; dg < 4; ++dg) {
            float v = O[dg][r] * inv;
            size_t off = ((size_t)qd * B_ + b) * EMBED + h * HDIM + dg * 16 + l15;
            unsigned short hb = f2bf(v);
            Chi_p[off] = hb;
            Clo_p[off] = f2bf(v - bf2f(hb));
        }
    }
}

// ---------------------------------------------------------------------------
extern "C" void kernel_launch(void* const* d_in, const int* in_sizes, int n_in,
                              void* d_out, int out_size, void* d_ws, size_t ws_size,
                              hipStream_t stream) {
    const float* utter = (const float*)d_in[0];
    const float* rctx  = (const float*)d_in[1];
    const float* summ  = (const float*)d_in[2];
    const float* mem   = (const float*)d_in[3];
    const int* amask   = (const int*)d_in[4];
    const int* pmask   = (const int*)d_in[5];
    const float* Wq  = (const float*)d_in[6];
    const float* bq  = (const float*)d_in[7];
    const float* Wkv = (const float*)d_in[8];
    const float* bkv = (const float*)d_in[9];
    const float* Wo  = (const float*)d_in[10];
    const float* bo  = (const float*)d_in[11];

    // SRC plane segment offsets (elements)
    const size_t UT_OFF = 0;                 // utter  8,388,608
    const size_t RC_OFF = 8388608;           // rctx   2,097,152
    const size_t SM_OFF = 10485760;          // summ     262,144
    const size_t MM_OFF = 10747904;          // mem      253,952
    const size_t SRC_N  = 11001856;
    // W plane offsets
    const size_t WQ_OFF = 0, WKV_OFF = 262144, WO_OFF = 786432;
    const size_t W_N = 1048576;

    ushort_t* p = (ushort_t*)d_ws;
    ushort_t* SRC_hi = p;                p += SRC_N;
    ushort_t* SRC_lo = p;                p += SRC_N;
    ushort_t* Wp_hi  = p;                p += W_N;
    ushort_t* Wp_lo  = p;                p += W_N;
    ushort_t* Qhi_p  = p;                p += (size_t)QROWS * EMBED;
    ushort_t* Qlo_p  = p;                p += (size_t)QROWS * EMBED;
    ushort_t* Khi_p  = p;                p += (size_t)KVROWS * EMBED;
    ushort_t* Klo_p  = p;                p += (size_t)KVROWS * EMBED;
    ushort_t* Vp     = p;                p += (size_t)KVROWS * EMBED;
    ushort_t* Chi_p  = p;                p += (size_t)QROWS * EMBED;
    ushort_t* Clo_p  = p;                p += (size_t)QROWS * EMBED;

    float* out0 = (float*)d_out;
    float* out1 = out0 + (size_t)OUT0_ROWS * EMBED;

    dim3 blk(256);

    // --- convert sources + weights to hi/lo planes
    auto cv = [&](const float* s, ushort_t* hi, ushort_t* lo, size_t n) {
        int n8 = (int)(n / 8);
        cvt_hilo<<<dim3((n8 + 255) / 256), blk, 0, stream>>>(s, hi, lo, n8);
    };
    cv(utter, SRC_hi + UT_OFF, SRC_lo + UT_OFF, (size_t)U_ * B_ * EMBED);
    cv(rctx,  SRC_hi + RC_OFF, SRC_lo + RC_OFF, (size_t)R_ * B_ * EMBED);
    cv(summ,  SRC_hi + SM_OFF, SRC_lo + SM_OFF, (size_t)S_ * B_ * EMBED);
    cv(mem,   SRC_hi + MM_OFF, SRC_lo + MM_OFF, (size_t)M_ * B_ * EMBED);
    cv(Wq,  Wp_hi + WQ_OFF,  Wp_lo + WQ_OFF,  (size_t)EMBED * EMBED);
    cv(Wkv, Wp_hi + WKV_OFF, Wp_lo + WKV_OFF, (size_t)2 * EMBED * EMBED);
    cv(Wo,  Wp_hi + WO_OFF,  Wp_lo + WO_OFF,  (size_t)EMBED * EMBED);

    // --- q projection: q_in = [rc | utter | summ], (x@Wq.T+bq)*0.125 -> hi/lo
    gemm_mfma<0><<<dim3(QROWS / 128, EMBED / 128), blk, 0, stream>>>(
        SRC_hi, SRC_lo, Wp_hi + WQ_OFF, Wp_lo + WQ_OFF, bq, 0.125f,
        R_ * B_, (R_ + U_) * B_, QROWS, RC_OFF, UT_OFF, SM_OFF,
        Qhi_p, Qlo_p, nullptr);

    // --- kv projection: kv_in = [mem | rc | utter] -> K hi/lo, V bf16
    gemm_mfma<1><<<dim3((KVROWS + 127) / 128, (2 * EMBED) / 128), blk, 0, stream>>>(
        SRC_hi, SRC_lo, Wp_hi + WKV_OFF, Wp_lo + WKV_OFF, bkv, 1.0f,
        M_ * B_, (M_ + R_) * B_, KVROWS, MM_OFF, RC_OFF, UT_OFF,
        Khi_p, Klo_p, Vp);

    // --- attention
    attn_mfma<<<dim3((Q_ + 63) / 64, B_ * NHEAD), blk, 0, stream>>>(
        Qhi_p, Qlo_p, Khi_p, Klo_p, Vp, amask, pmask, Chi_p, Clo_p);

    // --- out projection (+clip/split epilogue), ctx hi/lo -> fp32 d_out
    gemm_mfma<2><<<dim3(QROWS / 128, EMBED / 128), blk, 0, stream>>>(
        Chi_p, Clo_p, Wp_hi + WO_OFF, Wp_lo + WO_OFF, bo, 1.0f,
        QROWS, QROWS, QROWS, 0, 0, 0,
        out0, out1, nullptr);
}

// Round 6
// 509.759 us; speedup vs baseline: 11.6737x; 1.5878x over previous
//
#include <hip/hip_runtime.h>
#include <hip/hip_bf16.h>

#define EMBED 512
#define NHEAD 8
#define HDIM  64
#define B_    16
#define U_    1024
#define R_    256
#define S_    32
#define M_    31
#define Q_    (R_ + U_ + S_)   // 1312
#define KV_   (M_ + R_ + U_)   // 1311
#define NEG_INF_F (-100000000.0f)

#define QROWS  (Q_ * B_)        // 20992
#define KVROWS (KV_ * B_)       // 20976
#define OROWS  (1311 * B_)      // 20976
#define OUT0_ROWS (1280 * B_)   // 20480

#define KVPAD_ROWS 1344         // kv rows padded for OOB tile reads
#define MROWSTRIDE 44           // packed-mask row stride (words), 8B-aligned pairs

typedef __attribute__((ext_vector_type(8))) short bf16x8;
typedef __attribute__((ext_vector_type(4))) float f32x4;
#define MFMA16(a, b, c) __builtin_amdgcn_mfma_f32_16x16x32_bf16(a, b, c, 0, 0, 0)

typedef unsigned short ushort_t;

__device__ __forceinline__ unsigned short f2bf(float x) {
    unsigned u = __float_as_uint(x);
    u += 0x7fff + ((u >> 16) & 1);
    return (unsigned short)(u >> 16);
}
__device__ __forceinline__ float bf2f(unsigned short h) {
    return __uint_as_float((unsigned)h << 16);
}

__device__ __forceinline__ void gload_lds16(const void* g, void* l) {
    __builtin_amdgcn_global_load_lds(
        (const __attribute__((address_space(1))) unsigned int*)g,
        (__attribute__((address_space(3))) unsigned int*)l, 16, 0, 0);
}

// ---------------------------------------------------------------------------
// fp32 -> hi/lo bf16 split (8 elements / thread)
// ---------------------------------------------------------------------------
__global__ __launch_bounds__(256) void cvt_hilo(
    const float* __restrict__ src, ushort_t* __restrict__ hi,
    ushort_t* __restrict__ lo, int n8)
{
    int i = blockIdx.x * 256 + threadIdx.x;
    if (i >= n8) return;
    const float4* s = (const float4*)(src + (size_t)i * 8);
    float4 a = s[0], b2 = s[1];
    float xs[8] = {a.x, a.y, a.z, a.w, b2.x, b2.y, b2.z, b2.w};
    bf16x8 hv, lv;
    #pragma unroll
    for (int j = 0; j < 8; ++j) {
        unsigned short hb = f2bf(xs[j]);
        hv[j] = (short)hb;
        lv[j] = (short)f2bf(xs[j] - bf2f(hb));
    }
    *(bf16x8*)(hi + (size_t)i * 8) = hv;
    *(bf16x8*)(lo + (size_t)i * 8) = lv;
}

// ---------------------------------------------------------------------------
// Pack masks into bitmasks (bit=1 -> masked; kg>=KV bits set to 1),
// and zero V pad rows (so garbage never reaches PV through pad rows).
// ---------------------------------------------------------------------------
__global__ __launch_bounds__(256) void pack_aux(
    const int* __restrict__ am, const int* __restrict__ pm,
    unsigned* __restrict__ am_p, unsigned* __restrict__ pm_p,
    ushort_t* __restrict__ vpad)
{
    const int NA = Q_ * MROWSTRIDE;
    const int NP = B_ * MROWSTRIDE;
    const int NZ = (KVPAD_ROWS * B_ - KVROWS) * EMBED / 8;  // uint4 stores
    int idx = blockIdx.x * 256 + threadIdx.x;
    if (idx < NA) {
        int q = idx / MROWSTRIDE, w_ = idx % MROWSTRIDE;
        unsigned bits = 0xFFFFFFFFu;
        if (w_ < 41) {
            bits = 0;
            #pragma unroll 4
            for (int i = 0; i < 32; ++i) {
                int kg = w_ * 32 + i;
                int v = (kg < KV_) ? am[(size_t)q * KV_ + kg] : 1;
                bits |= (unsigned)(v != 0) << i;
            }
        }
        am_p[idx] = bits;
    } else if (idx < NA + NP) {
        int j = idx - NA;
        int bb = j / MROWSTRIDE, w_ = j % MROWSTRIDE;
        unsigned bits = 0xFFFFFFFFu;
        if (w_ < 41) {
            bits = 0;
            #pragma unroll 4
            for (int i = 0; i < 32; ++i) {
                int kg = w_ * 32 + i;
                int v = (kg < KV_) ? pm[bb * KV_ + kg] : 1;
                bits |= (unsigned)(v != 0) << i;
            }
        }
        pm_p[j] = bits;
    } else if (idx < NA + NP + NZ) {
        int k = idx - NA - NP;
        ((uint4*)vpad)[k] = make_uint4(0, 0, 0, 0);
    }
}

// ---------------------------------------------------------------------------
// MFMA projection GEMM, hi/lo split operands (fp32-accurate: 3-term).
// (unchanged from round 4)
// ---------------------------------------------------------------------------
template<int MODE>
__global__ __launch_bounds__(256) void gemm_mfma(
    const ushort_t* __restrict__ Ahi, const ushort_t* __restrict__ Alo,
    const ushort_t* __restrict__ Whi, const ushort_t* __restrict__ Wlo,
    const float* __restrict__ bias, float scale,
    int n0, int n01, int nrows,
    size_t off0, size_t off1, size_t off2,
    void* __restrict__ o0, void* __restrict__ o1, void* __restrict__ o2)
{
    __shared__ __align__(16) ushort_t lAhi[128][64];
    __shared__ __align__(16) ushort_t lAlo[128][64];
    __shared__ __align__(16) ushort_t lWhi[128][64];
    __shared__ __align__(16) ushort_t lWlo[128][64];

    const int tid = threadIdx.x;
    const int w   = tid >> 6;
    const int l   = tid & 63;
    const int l15 = l & 15;
    const int l4  = l >> 4;
    const int row0 = blockIdx.x * 128;
    const int col0 = blockIdx.y * 128;

    const int drow = l >> 3;
    const int sgr  = (l & 7) ^ drow;
    const ushort_t* aptr[4];
    const ushort_t* wptr[4];
    #pragma unroll
    for (int c = 0; c < 4; ++c) {
        int r = row0 + w * 32 + c * 8 + drow;
        int rc = r < nrows ? r : nrows - 1;
        size_t roff;
        if (MODE == 2)      roff = (size_t)rc * EMBED;
        else if (rc < n0)   roff = off0 + (size_t)rc * EMBED;
        else if (rc < n01)  roff = off1 + (size_t)(rc - n0) * EMBED;
        else                roff = off2 + (size_t)(rc - n01) * EMBED;
        aptr[c] = Ahi + roff + sgr * 8;
        int wr = col0 + w * 32 + c * 8 + drow;
        wptr[c] = Whi + (size_t)wr * EMBED + sgr * 8;
    }
    const ptrdiff_t dA = Alo - Ahi;
    const ptrdiff_t dW = Wlo - Whi;

    f32x4 acc[4][4];
    #pragma unroll
    for (int mi = 0; mi < 4; ++mi)
        #pragma unroll
        for (int nj = 0; nj < 4; ++nj) acc[mi][nj] = (f32x4){0.f, 0.f, 0.f, 0.f};

    const int wrow = (w >> 1) * 64;
    const int wcol = (w & 1) * 64;

    for (int t = 0; t < 8; ++t) {
        __syncthreads();
        const int ke = t * 64;
        #pragma unroll
        for (int c = 0; c < 4; ++c) {
            gload_lds16(aptr[c] + ke,      &lAhi[w * 32 + c * 8][0]);
            gload_lds16(aptr[c] + ke + dA, &lAlo[w * 32 + c * 8][0]);
            gload_lds16(wptr[c] + ke,      &lWhi[w * 32 + c * 8][0]);
            gload_lds16(wptr[c] + ke + dW, &lWlo[w * 32 + c * 8][0]);
        }
        __syncthreads();

        #pragma unroll
        for (int kk = 0; kk < 2; ++kk) {
            bf16x8 ah[4], al_[4], wh[4], wl[4];
            #pragma unroll
            for (int mi = 0; mi < 4; ++mi) {
                int row = wrow + mi * 16 + l15;
                int g = (((kk * 4 + l4) ^ (l15 & 7))) * 8;
                ah[mi]  = *(const bf16x8*)&lAhi[row][g];
                al_[mi] = *(const bf16x8*)&lAlo[row][g];
            }
            #pragma unroll
            for (int nj = 0; nj < 4; ++nj) {
                int row = wcol + nj * 16 + l15;
                int g = (((kk * 4 + l4) ^ (l15 & 7))) * 8;
                wh[nj] = *(const bf16x8*)&lWhi[row][g];
                wl[nj] = *(const bf16x8*)&lWlo[row][g];
            }
            #pragma unroll
            for (int mi = 0; mi < 4; ++mi)
                #pragma unroll
                for (int nj = 0; nj < 4; ++nj) {
                    acc[mi][nj] = MFMA16(ah[mi],  wh[nj], acc[mi][nj]);
                    acc[mi][nj] = MFMA16(al_[mi], wh[nj], acc[mi][nj]);
                    acc[mi][nj] = MFMA16(ah[mi],  wl[nj], acc[mi][nj]);
                }
        }
    }

    #pragma unroll
    for (int nj = 0; nj < 4; ++nj) {
        int gc = col0 + wcol + nj * 16 + l15;
        float bv = bias[gc];
        #pragma unroll
        for (int mi = 0; mi < 4; ++mi) {
            #pragma unroll
            for (int r = 0; r < 4; ++r) {
                int gr = row0 + wrow + mi * 16 + l4 * 4 + r;
                if (gr >= nrows) continue;
                float v = (acc[mi][nj][r] + bv) * scale;
                if (MODE == 0) {
                    unsigned short hb = f2bf(v);
                    ((ushort_t*)o0)[(size_t)gr * EMBED + gc] = hb;
                    ((ushort_t*)o1)[(size_t)gr * EMBED + gc] = f2bf(v - bf2f(hb));
                } else if (MODE == 1) {
                    if (gc < EMBED) {
                        unsigned short hb = f2bf(v);
                        ((ushort_t*)o0)[(size_t)gr * EMBED + gc] = hb;
                        ((ushort_t*)o1)[(size_t)gr * EMBED + gc] = f2bf(v - bf2f(hb));
                    } else {
                        ((ushort_t*)o2)[(size_t)gr * EMBED + (gc - EMBED)] = f2bf(v);
                    }
                } else {
                    if (gr < OUT0_ROWS)
                        ((float*)o0)[(size_t)gr * EMBED + gc] = v;
                    else if (gr < OROWS)
                        ((float*)o1)[(size_t)(gr - OUT0_ROWS) * EMBED + gc] =
                            fminf(fmaxf(v, -10.f), 10.f);
                }
            }
        }
    }
}

// ---------------------------------------------------------------------------
// MFMA flash attention, KVBLK=64, double-buffered LDS.
// K: gload_lds, source-swizzled granules (g ^= row&7), read via swizzled b128.
// V: reg-staged transpose into Vt[d][col] with XOR-swizzled col blocks
//    (colblk ^= d>>3). Writes: ushort2, 2 lanes/bank (free). Reads: b128,
//    8 lanes per 4-bank slot (conflict-free-equivalent).
// QK^T 2-term: (Qhi + Qlo) x Khi. Masks: packed bitmask words.
// T14: V global loads for tile kt+1 issued before QK^T, LDS write after PV.
// ---------------------------------------------------------------------------
__global__ __launch_bounds__(256) void attn_mfma(
    const ushort_t* __restrict__ Qhi_p, const ushort_t* __restrict__ Qlo_p,
    const ushort_t* __restrict__ Khi_p, const ushort_t* __restrict__ Vp,
    const unsigned* __restrict__ am_p, const unsigned* __restrict__ pm_p,
    ushort_t* __restrict__ Chi_p, ushort_t* __restrict__ Clo_p)
{
    __shared__ __align__(16) ushort_t Kl[2][64][64];   // 16 KB
    __shared__ __align__(16) ushort_t Vt[2][64][64];   // 16 KB (col-swizzled)
    __shared__ __align__(16) ushort_t Pb[4][16][72];   // 9 KB

    const int tid = threadIdx.x;
    const int w   = tid >> 6;
    const int l   = tid & 63;
    const int l15 = l & 15;
    const int l4  = l >> 4;
    const int q0  = blockIdx.x * 64;
    const int bh  = blockIdx.y;
    const int b   = bh >> 3, h = bh & 7;

    // --- Q fragments (hoisted)
    bf16x8 Qhi[2], Qlo[2];
    {
        int qa = q0 + w * 16 + l15;
        if (qa >= Q_) qa = Q_ - 1;
        size_t base = ((size_t)qa * B_ + b) * EMBED + h * HDIM;
        #pragma unroll
        for (int dh = 0; dh < 2; ++dh) {
            Qhi[dh] = *(const bf16x8*)(Qhi_p + base + dh * 32 + l4 * 8);
            Qlo[dh] = *(const bf16x8*)(Qlo_p + base + dh * 32 + l4 * 8);
        }
    }

    // --- staging geometry
    const int krl  = l >> 3;               // K: row within 8-row chunk
    const int kgr0 = l & 7;                // K: LDS granule
    const int vk2  = 2 * (tid >> 3);       // V: k-pair owned (0,2,..,62)
    const int vsg  = tid & 7;              // V: d-granule (d = vsg*8+j)
    const int vcol = ((((vk2 >> 3) ^ vsg) << 3) | (vk2 & 7));  // swizzled col

    float m[4]    = {-INFINITY, -INFINITY, -INFINITY, -INFINITY};
    float ssum[4] = {0.f, 0.f, 0.f, 0.f};
    f32x4 O[4];
    #pragma unroll
    for (int dg = 0; dg < 4; ++dg) O[dg] = (f32x4){0.f, 0.f, 0.f, 0.f};

    auto stageK = [&](int kbase, int buf) {
        #pragma unroll
        for (int p = 0; p < 2; ++p) {
            int row = w * 16 + p * 8 + krl;
            int gsrc = kgr0 ^ (row & 7);
            const ushort_t* src =
                Khi_p + ((size_t)(kbase + row) * B_ + b) * EMBED + h * HDIM + gsrc * 8;
            gload_lds16(src, &Kl[buf][w * 16 + p * 8][0]);
        }
    };
    auto loadV = [&](int kbase, bf16x8& va, bf16x8& vb) {
        size_t r0 = ((size_t)(kbase + vk2) * B_ + b) * EMBED + h * HDIM + vsg * 8;
        va = *(const bf16x8*)(Vp + r0);
        vb = *(const bf16x8*)(Vp + r0 + (size_t)B_ * EMBED);
    };
    auto writeV = [&](int buf, bf16x8 va, bf16x8 vb) {
        #pragma unroll
        for (int j = 0; j < 8; ++j) {
            int d = vsg * 8 + j;
            ushort2 t2;
            t2.x = (ushort_t)va[j];
            t2.y = (ushort_t)vb[j];
            *(ushort2*)&Vt[buf][d][vcol] = t2;
        }
    };

    // --- prologue: tile 0
    {
        bf16x8 va, vb;
        stageK(0, 0);
        loadV(0, va, vb);
        writeV(0, va, vb);
    }
    __syncthreads();
    int cur = 0;

    for (int kt = 0; kt < 21; ++kt) {
        const int k0 = kt * 64;

        // --- masks for this tile
        uint2 pw = *(const uint2*)&pm_p[b * MROWSTRIDE + 2 * kt];
        uint2 aw[4];
        #pragma unroll
        for (int r = 0; r < 4; ++r) {
            int q = q0 + w * 16 + l4 * 4 + r;
            if (q >= Q_) q = Q_ - 1;
            aw[r] = *(const uint2*)&am_p[(size_t)q * MROWSTRIDE + 2 * kt];
        }

        // --- issue next-tile staging (K direct to LDS; V to regs, write later)
        bf16x8 nva, nvb;
        if (kt < 20) {
            stageK(k0 + 64, cur ^ 1);
            loadV(k0 + 64, nva, nvb);
        }

        // --- QK^T: 2-term (Qhi + Qlo) x Khi
        f32x4 S[4];
        #pragma unroll
        for (int c = 0; c < 4; ++c) {
            f32x4 acc = (f32x4){0.f, 0.f, 0.f, 0.f};
            int krow = c * 16 + l15;
            #pragma unroll
            for (int dh = 0; dh < 2; ++dh) {
                int gr = ((dh * 4 + l4) ^ (krow & 7)) * 8;
                bf16x8 Bh = *(const bf16x8*)&Kl[cur][krow][gr];
                acc = MFMA16(Qhi[dh], Bh, acc);
                acc = MFMA16(Qlo[dh], Bh, acc);
            }
            S[c] = acc;
        }

        // --- masks + online softmax (rows q=l4*4+r, cols c*16+l15)
        float p_[4][4];   // [c][r]
        float al[4];
        #pragma unroll
        for (int r = 0; r < 4; ++r) {
            unsigned m0 = aw[r].x | pw.x;
            unsigned m1 = aw[r].y | pw.y;
            float t = -INFINITY;
            #pragma unroll
            for (int c = 0; c < 4; ++c) {
                int kg = k0 + c * 16 + l15;
                unsigned half = (c & 2) ? m1 : m0;
                float s = S[c][r];
                if ((half >> (((c & 1) << 4) + l15)) & 1) s = NEG_INF_F;
                if (kg >= KV_) s = -INFINITY;
                p_[c][r] = s;
                t = fmaxf(t, s);
            }
            #pragma unroll
            for (int msk = 1; msk < 16; msk <<= 1) t = fmaxf(t, __shfl_xor(t, msk, 64));
            float mn = fmaxf(m[r], t);
            al[r] = __expf(m[r] - mn);
            m[r] = mn;
            float ps = 0.f;
            #pragma unroll
            for (int c = 0; c < 4; ++c) {
                float pe = __expf(p_[c][r] - mn);
                p_[c][r] = pe;
                ps += pe;
            }
            #pragma unroll
            for (int msk = 1; msk < 16; msk <<= 1) ps += __shfl_xor(ps, msk, 64);
            ssum[r] = ssum[r] * al[r] + ps;
        }

        // --- P -> per-wave LDS (bf16)
        #pragma unroll
        for (int r = 0; r < 4; ++r) {
            int qr = l4 * 4 + r;
            #pragma unroll
            for (int c = 0; c < 4; ++c)
                Pb[w][qr][c * 16 + l15] = f2bf(p_[c][r]);
        }

        // --- O rescale
        #pragma unroll
        for (int dg = 0; dg < 4; ++dg)
            #pragma unroll
            for (int r = 0; r < 4; ++r) O[dg][r] *= al[r];

        // --- PA fragments
        bf16x8 PA[2];
        #pragma unroll
        for (int kh = 0; kh < 2; ++kh)
            PA[kh] = *(const bf16x8*)&Pb[w][l15][kh * 32 + l4 * 8];

        // --- PV: swizzled Vt reads (b128), 8 MFMA
        #pragma unroll
        for (int kh = 0; kh < 2; ++kh)
            #pragma unroll
            for (int dg = 0; dg < 4; ++dg) {
                int vcb = (((kh * 4 + l4) ^ (dg * 2 + (l15 >> 3)))) << 3;
                bf16x8 VB = *(const bf16x8*)&Vt[cur][dg * 16 + l15][vcb];
                O[dg] = MFMA16(PA[kh], VB, O[dg]);
            }

        // --- deferred V write for next tile (T14)
        if (kt < 20) writeV(cur ^ 1, nva, nvb);

        __syncthreads();
        cur ^= 1;
    }

    // --- epilogue: write ctx hi/lo planes
    #pragma unroll
    for (int r = 0; r < 4; ++r) {
        int qd = q0 + w * 16 + l4 * 4 + r;
        if (qd >= Q_) continue;
        float inv = 1.f / ssum[r];
        #pragma unroll
        for (int dg = 0; dg < 4; ++dg) {
            float v = O[dg][r] * inv;
            size_t off = ((size_t)qd * B_ + b) * EMBED + h * HDIM + dg * 16 + l15;
            unsigned short hb = f2bf(v);
            Chi_p[off] = hb;
            Clo_p[off] = f2bf(v - bf2f(hb));
        }
    }
}

// ---------------------------------------------------------------------------
extern "C" void kernel_launch(void* const* d_in, const int* in_sizes, int n_in,
                              void* d_out, int out_size, void* d_ws, size_t ws_size,
                              hipStream_t stream) {
    const float* utter = (const float*)d_in[0];
    const float* rctx  = (const float*)d_in[1];
    const float* summ  = (const float*)d_in[2];
    const float* mem   = (const float*)d_in[3];
    const int* amask   = (const int*)d_in[4];
    const int* pmask   = (const int*)d_in[5];
    const float* Wq  = (const float*)d_in[6];
    const float* bq  = (const float*)d_in[7];
    const float* Wkv = (const float*)d_in[8];
    const float* bkv = (const float*)d_in[9];
    const float* Wo  = (const float*)d_in[10];
    const float* bo  = (const float*)d_in[11];

    const size_t UT_OFF = 0;
    const size_t RC_OFF = 8388608;
    const size_t SM_OFF = 10485760;
    const size_t MM_OFF = 10747904;
    const size_t SRC_N  = 11001856;
    const size_t WQ_OFF = 0, WKV_OFF = 262144, WO_OFF = 786432;
    const size_t W_N = 1048576;
    const size_t KVPLANE = (size_t)KVPAD_ROWS * B_ * EMBED;   // padded rows

    ushort_t* p = (ushort_t*)d_ws;
    ushort_t* SRC_hi = p;                p += SRC_N;
    ushort_t* SRC_lo = p;                p += SRC_N;
    ushort_t* Wp_hi  = p;                p += W_N;
    ushort_t* Wp_lo  = p;                p += W_N;
    ushort_t* Qhi_p  = p;                p += (size_t)QROWS * EMBED;
    ushort_t* Qlo_p  = p;                p += (size_t)QROWS * EMBED;
    ushort_t* Khi_p  = p;                p += KVPLANE;
    ushort_t* Klo_p  = p;                p += KVPLANE;
    ushort_t* Vp     = p;                p += KVPLANE;
    ushort_t* Chi_p  = p;                p += (size_t)QROWS * EMBED;
    ushort_t* Clo_p  = p;                p += (size_t)QROWS * EMBED;
    unsigned* am_p   = (unsigned*)p;     p += (size_t)2 * KVPAD_ROWS * MROWSTRIDE;
    unsigned* pm_p   = (unsigned*)p;     p += (size_t)2 * B_ * MROWSTRIDE;

    float* out0 = (float*)d_out;
    float* out1 = out0 + (size_t)OUT0_ROWS * EMBED;

    dim3 blk(256);

    auto cv = [&](const float* s, ushort_t* hi, ushort_t* lo, size_t n) {
        int n8 = (int)(n / 8);
        cvt_hilo<<<dim3((n8 + 255) / 256), blk, 0, stream>>>(s, hi, lo, n8);
    };
    cv(utter, SRC_hi + UT_OFF, SRC_lo + UT_OFF, (size_t)U_ * B_ * EMBED);
    cv(rctx,  SRC_hi + RC_OFF, SRC_lo + RC_OFF, (size_t)R_ * B_ * EMBED);
    cv(summ,  SRC_hi + SM_OFF, SRC_lo + SM_OFF, (size_t)S_ * B_ * EMBED);
    cv(mem,   SRC_hi + MM_OFF, SRC_lo + MM_OFF, (size_t)M_ * B_ * EMBED);
    cv(Wq,  Wp_hi + WQ_OFF,  Wp_lo + WQ_OFF,  (size_t)EMBED * EMBED);
    cv(Wkv, Wp_hi + WKV_OFF, Wp_lo + WKV_OFF, (size_t)2 * EMBED * EMBED);
    cv(Wo,  Wp_hi + WO_OFF,  Wp_lo + WO_OFF,  (size_t)EMBED * EMBED);

    // pack masks + zero V pad rows
    {
        int total = Q_ * MROWSTRIDE + B_ * MROWSTRIDE +
                    (KVPAD_ROWS * B_ - KVROWS) * EMBED / 8;
        pack_aux<<<dim3((total + 255) / 256), blk, 0, stream>>>(
            amask, pmask, am_p, pm_p, Vp + (size_t)KVROWS * EMBED);
    }

    gemm_mfma<0><<<dim3(QROWS / 128, EMBED / 128), blk, 0, stream>>>(
        SRC_hi, SRC_lo, Wp_hi + WQ_OFF, Wp_lo + WQ_OFF, bq, 0.125f,
        R_ * B_, (R_ + U_) * B_, QROWS, RC_OFF, UT_OFF, SM_OFF,
        Qhi_p, Qlo_p, nullptr);

    gemm_mfma<1><<<dim3((KVROWS + 127) / 128, (2 * EMBED) / 128), blk, 0, stream>>>(
        SRC_hi, SRC_lo, Wp_hi + WKV_OFF, Wp_lo + WKV_OFF, bkv, 1.0f,
        M_ * B_, (M_ + R_) * B_, KVROWS, MM_OFF, RC_OFF, UT_OFF,
        Khi_p, Klo_p, Vp);

    attn_mfma<<<dim3((Q_ + 63) / 64, B_ * NHEAD), blk, 0, stream>>>(
        Qhi_p, Qlo_p, Khi_p, Vp, am_p, pm_p, Chi_p, Clo_p);

    gemm_mfma<2><<<dim3(QROWS / 128, EMBED / 128), blk, 0, stream>>>(
        Chi_p, Clo_p, Wp_hi + WO_OFF, Wp_lo + WO_OFF, bo, 1.0f,
        QROWS, QROWS, QROWS, 0, 0, 0,
        out0, out1, nullptr);
}

// Round 7
// 461.601 us; speedup vs baseline: 12.8916x; 1.1043x over previous
//
#include <hip/hip_runtime.h>
#include <hip/hip_bf16.h>

#define EMBED 512
#define NHEAD 8
#define HDIM  64
#define B_    16
#define U_    1024
#define R_    256
#define S_    32
#define M_    31
#define Q_    (R_ + U_ + S_)   // 1312
#define KV_   (M_ + R_ + U_)   // 1311
#define NEG_INF_F (-100000000.0f)

#define QROWS  (Q_ * B_)        // 20992
#define KVROWS (KV_ * B_)       // 20976
#define OROWS  (1311 * B_)      // 20976
#define OUT0_ROWS (1280 * B_)   // 20480

#define KVPAD_ROWS 1344         // kv rows padded for OOB tile reads
#define KPAD 1344               // VT row length (k padded)
#define MROWSTRIDE 44           // packed-mask row stride (words)

typedef __attribute__((ext_vector_type(8))) short bf16x8;
typedef __attribute__((ext_vector_type(4))) float f32x4;
#define MFMA16(a, b, c) __builtin_amdgcn_mfma_f32_16x16x32_bf16(a, b, c, 0, 0, 0)

typedef unsigned short ushort_t;

__device__ __forceinline__ unsigned short f2bf(float x) {
    unsigned u = __float_as_uint(x);
    u += 0x7fff + ((u >> 16) & 1);
    return (unsigned short)(u >> 16);
}
__device__ __forceinline__ float bf2f(unsigned short h) {
    return __uint_as_float((unsigned)h << 16);
}

__device__ __forceinline__ void gload_lds16(const void* g, void* l) {
    __builtin_amdgcn_global_load_lds(
        (const __attribute__((address_space(1))) unsigned int*)g,
        (__attribute__((address_space(3))) unsigned int*)l, 16, 0, 0);
}

// ---------------------------------------------------------------------------
// fp32 -> hi/lo bf16 split (8 elements / thread)
// ---------------------------------------------------------------------------
__global__ __launch_bounds__(256) void cvt_hilo(
    const float* __restrict__ src, ushort_t* __restrict__ hi,
    ushort_t* __restrict__ lo, int n8)
{
    int i = blockIdx.x * 256 + threadIdx.x;
    if (i >= n8) return;
    const float4* s = (const float4*)(src + (size_t)i * 8);
    float4 a = s[0], b2 = s[1];
    float xs[8] = {a.x, a.y, a.z, a.w, b2.x, b2.y, b2.z, b2.w};
    bf16x8 hv, lv;
    #pragma unroll
    for (int j = 0; j < 8; ++j) {
        unsigned short hb = f2bf(xs[j]);
        hv[j] = (short)hb;
        lv[j] = (short)f2bf(xs[j] - bf2f(hb));
    }
    *(bf16x8*)(hi + (size_t)i * 8) = hv;
    *(bf16x8*)(lo + (size_t)i * 8) = lv;
}

// ---------------------------------------------------------------------------
// Pack masks into bitmasks (bit=1 -> masked; kg>=KV bits set to 1).
// ---------------------------------------------------------------------------
__global__ __launch_bounds__(256) void pack_aux(
    const int* __restrict__ am, const int* __restrict__ pm,
    unsigned* __restrict__ am_p, unsigned* __restrict__ pm_p)
{
    const int NA = Q_ * MROWSTRIDE;
    const int NP = B_ * MROWSTRIDE;
    int idx = blockIdx.x * 256 + threadIdx.x;
    if (idx < NA) {
        int q = idx / MROWSTRIDE, w_ = idx % MROWSTRIDE;
        unsigned bits = 0xFFFFFFFFu;
        if (w_ < 41) {
            bits = 0;
            #pragma unroll 4
            for (int i = 0; i < 32; ++i) {
                int kg = w_ * 32 + i;
                int v = (kg < KV_) ? am[(size_t)q * KV_ + kg] : 1;
                bits |= (unsigned)(v != 0) << i;
            }
        }
        am_p[idx] = bits;
    } else if (idx < NA + NP) {
        int j = idx - NA;
        int bb = j / MROWSTRIDE, w_ = j % MROWSTRIDE;
        unsigned bits = 0xFFFFFFFFu;
        if (w_ < 41) {
            bits = 0;
            #pragma unroll 4
            for (int i = 0; i < 32; ++i) {
                int kg = w_ * 32 + i;
                int v = (kg < KV_) ? pm[bb * KV_ + kg] : 1;
                bits |= (unsigned)(v != 0) << i;
            }
        }
        pm_p[j] = bits;
    }
}

// ---------------------------------------------------------------------------
// V transpose: Vp[kvrow = k*16+b][h*64+d]  ->  VT[(b*8+h)*64 + d][k]
// k padded to KPAD with zeros. LDS-tiled, coalesced both sides.
// ---------------------------------------------------------------------------
__global__ __launch_bounds__(256) void vtrans(
    const ushort_t* __restrict__ Vp, ushort_t* __restrict__ VT)
{
    __shared__ ushort_t Lt[64][72];
    const int tid = threadIdx.x;
    const int kt  = blockIdx.x;          // 0..20
    const int bh  = blockIdx.y;          // 0..127
    const int b   = bh >> 3, h = bh & 7;
    const int sub = tid >> 3;            // 0..31
    const int g   = tid & 7;

    #pragma unroll
    for (int p = 0; p < 2; ++p) {
        int k = kt * 64 + p * 32 + sub;
        bf16x8 v;
        if (k < KV_) {
            v = *(const bf16x8*)(Vp + ((size_t)k * B_ + b) * EMBED + h * HDIM + g * 8);
        } else {
            #pragma unroll
            for (int j = 0; j < 8; ++j) v[j] = 0;
        }
        #pragma unroll
        for (int j = 0; j < 8; ++j)
            Lt[g * 8 + j][p * 32 + sub] = (ushort_t)v[j];
    }
    __syncthreads();
    #pragma unroll
    for (int p = 0; p < 2; ++p) {
        int d = p * 32 + sub;
        bf16x8 v = *(const bf16x8*)&Lt[d][g * 8];
        *(bf16x8*)(VT + ((size_t)(bh * 64 + d)) * KPAD + kt * 64 + g * 8) = v;
    }
}

// ---------------------------------------------------------------------------
// MFMA projection GEMM, hi/lo split operands.
// TERMS = 3 (fp32-accurate) for MODE 0/2; TERMS = 2 for MODE 1 (outputs are
// consumed as plain bf16 -> dropped ah*wl term is sub-ulp).
// MODE 0: out = q hi/lo planes. MODE 1: cols<512 -> K bf16, else V bf16.
// MODE 2: fp32 out0 / clipped out1, row split.
// ---------------------------------------------------------------------------
template<int MODE>
__global__ __launch_bounds__(256) void gemm_mfma(
    const ushort_t* __restrict__ Ahi, const ushort_t* __restrict__ Alo,
    const ushort_t* __restrict__ Whi, const ushort_t* __restrict__ Wlo,
    const float* __restrict__ bias, float scale,
    int n0, int n01, int nrows,
    size_t off0, size_t off1, size_t off2,
    void* __restrict__ o0, void* __restrict__ o1, void* __restrict__ o2)
{
    constexpr int TERMS = (MODE == 1) ? 2 : 3;
    __shared__ __align__(16) ushort_t lAhi[128][64];
    __shared__ __align__(16) ushort_t lAlo[128][64];
    __shared__ __align__(16) ushort_t lWhi[128][64];
    __shared__ __align__(16) ushort_t lWlo[(TERMS == 3) ? 128 : 1][64];

    const int tid = threadIdx.x;
    const int w   = tid >> 6;
    const int l   = tid & 63;
    const int l15 = l & 15;
    const int l4  = l >> 4;
    const int row0 = blockIdx.x * 128;
    const int col0 = blockIdx.y * 128;

    const int drow = l >> 3;
    const int sgr  = (l & 7) ^ drow;
    const ushort_t* aptr[4];
    const ushort_t* wptr[4];
    #pragma unroll
    for (int c = 0; c < 4; ++c) {
        int r = row0 + w * 32 + c * 8 + drow;
        int rc = r < nrows ? r : nrows - 1;
        size_t roff;
        if (MODE == 2)      roff = (size_t)rc * EMBED;
        else if (rc < n0)   roff = off0 + (size_t)rc * EMBED;
        else if (rc < n01)  roff = off1 + (size_t)(rc - n0) * EMBED;
        else                roff = off2 + (size_t)(rc - n01) * EMBED;
        aptr[c] = Ahi + roff + sgr * 8;
        int wr = col0 + w * 32 + c * 8 + drow;
        wptr[c] = Whi + (size_t)wr * EMBED + sgr * 8;
    }
    const ptrdiff_t dA = Alo - Ahi;
    const ptrdiff_t dW = Wlo - Whi;

    f32x4 acc[4][4];
    #pragma unroll
    for (int mi = 0; mi < 4; ++mi)
        #pragma unroll
        for (int nj = 0; nj < 4; ++nj) acc[mi][nj] = (f32x4){0.f, 0.f, 0.f, 0.f};

    const int wrow = (w >> 1) * 64;
    const int wcol = (w & 1) * 64;

    for (int t = 0; t < 8; ++t) {
        __syncthreads();
        const int ke = t * 64;
        #pragma unroll
        for (int c = 0; c < 4; ++c) {
            gload_lds16(aptr[c] + ke,      &lAhi[w * 32 + c * 8][0]);
            gload_lds16(aptr[c] + ke + dA, &lAlo[w * 32 + c * 8][0]);
            gload_lds16(wptr[c] + ke,      &lWhi[w * 32 + c * 8][0]);
            if (TERMS == 3)
                gload_lds16(wptr[c] + ke + dW, &lWlo[w * 32 + c * 8][0]);
        }
        __syncthreads();

        #pragma unroll
        for (int kk = 0; kk < 2; ++kk) {
            bf16x8 ah[4], al_[4], wh[4], wl[4];
            #pragma unroll
            for (int mi = 0; mi < 4; ++mi) {
                int row = wrow + mi * 16 + l15;
                int g = (((kk * 4 + l4) ^ (l15 & 7))) * 8;
                ah[mi]  = *(const bf16x8*)&lAhi[row][g];
                al_[mi] = *(const bf16x8*)&lAlo[row][g];
            }
            #pragma unroll
            for (int nj = 0; nj < 4; ++nj) {
                int row = wcol + nj * 16 + l15;
                int g = (((kk * 4 + l4) ^ (l15 & 7))) * 8;
                wh[nj] = *(const bf16x8*)&lWhi[row][g];
                if (TERMS == 3) wl[nj] = *(const bf16x8*)&lWlo[row][g];
            }
            #pragma unroll
            for (int mi = 0; mi < 4; ++mi)
                #pragma unroll
                for (int nj = 0; nj < 4; ++nj) {
                    acc[mi][nj] = MFMA16(ah[mi],  wh[nj], acc[mi][nj]);
                    acc[mi][nj] = MFMA16(al_[mi], wh[nj], acc[mi][nj]);
                    if (TERMS == 3)
                        acc[mi][nj] = MFMA16(ah[mi], wl[nj], acc[mi][nj]);
                }
        }
    }

    #pragma unroll
    for (int nj = 0; nj < 4; ++nj) {
        int gc = col0 + wcol + nj * 16 + l15;
        float bv = bias[gc];
        #pragma unroll
        for (int mi = 0; mi < 4; ++mi) {
            #pragma unroll
            for (int r = 0; r < 4; ++r) {
                int gr = row0 + wrow + mi * 16 + l4 * 4 + r;
                if (gr >= nrows) continue;
                float v = (acc[mi][nj][r] + bv) * scale;
                if (MODE == 0) {
                    unsigned short hb = f2bf(v);
                    ((ushort_t*)o0)[(size_t)gr * EMBED + gc] = hb;
                    ((ushort_t*)o1)[(size_t)gr * EMBED + gc] = f2bf(v - bf2f(hb));
                } else if (MODE == 1) {
                    if (gc < EMBED)
                        ((ushort_t*)o0)[(size_t)gr * EMBED + gc] = f2bf(v);
                    else
                        ((ushort_t*)o2)[(size_t)gr * EMBED + (gc - EMBED)] = f2bf(v);
                } else {
                    if (gr < OUT0_ROWS)
                        ((float*)o0)[(size_t)gr * EMBED + gc] = v;
                    else if (gr < OROWS)
                        ((float*)o1)[(size_t)(gr - OUT0_ROWS) * EMBED + gc] =
                            fminf(fmaxf(v, -10.f), 10.f);
                }
            }
        }
    }
}

// ---------------------------------------------------------------------------
// MFMA flash attention, KVBLK=64, double-buffered LDS.
// K: gload_lds, source-swizzled granules (g ^= row&7), swizzled b128 reads.
// V: pre-transposed VT[bh*64+d][k] in global; staged via gload_lds with
//    pre-swizzled source granule (g = (l&7)^(l>>3)); read at
//    granule (kh*4+l4) ^ (l15&7)  -> conflict-free per 8-lane phase.
// QK^T 2-term: (Qhi + Qlo) x K. Masks: packed bitmask words.
// ---------------------------------------------------------------------------
__global__ __launch_bounds__(256) void attn_mfma(
    const ushort_t* __restrict__ Qhi_p, const ushort_t* __restrict__ Qlo_p,
    const ushort_t* __restrict__ Khi_p, const ushort_t* __restrict__ VT,
    const unsigned* __restrict__ am_p, const unsigned* __restrict__ pm_p,
    ushort_t* __restrict__ Chi_p, ushort_t* __restrict__ Clo_p)
{
    __shared__ __align__(16) ushort_t Kl[2][64][64];   // 16 KB
    __shared__ __align__(16) ushort_t Vt[2][64][64];   // 16 KB  rows=d, cols=k
    __shared__ __align__(16) ushort_t Pb[4][16][72];   // 9 KB

    const int tid = threadIdx.x;
    const int w   = tid >> 6;
    const int l   = tid & 63;
    const int l15 = l & 15;
    const int l4  = l >> 4;
    const int q0  = blockIdx.x * 64;
    const int bh  = blockIdx.y;
    const int b   = bh >> 3, h = bh & 7;

    // --- Q fragments (hoisted)
    bf16x8 Qhi[2], Qlo[2];
    {
        int qa = q0 + w * 16 + l15;
        if (qa >= Q_) qa = Q_ - 1;
        size_t base = ((size_t)qa * B_ + b) * EMBED + h * HDIM;
        #pragma unroll
        for (int dh = 0; dh < 2; ++dh) {
            Qhi[dh] = *(const bf16x8*)(Qhi_p + base + dh * 32 + l4 * 8);
            Qlo[dh] = *(const bf16x8*)(Qlo_p + base + dh * 32 + l4 * 8);
        }
    }

    // --- staging geometry (both K and V): lane covers row (l>>3), granule l&7
    const int krl  = l >> 3;
    const int gsrc = (l & 7) ^ krl;        // pre-swizzled source granule

    float m[4]    = {-INFINITY, -INFINITY, -INFINITY, -INFINITY};
    float ssum[4] = {0.f, 0.f, 0.f, 0.f};
    f32x4 O[4];
    #pragma unroll
    for (int dg = 0; dg < 4; ++dg) O[dg] = (f32x4){0.f, 0.f, 0.f, 0.f};

    auto stage = [&](int kbase, int buf) {
        #pragma unroll
        for (int p = 0; p < 2; ++p) {
            int row = w * 16 + p * 8 + krl;          // row&7 == krl
            const ushort_t* srcK =
                Khi_p + ((size_t)(kbase + row) * B_ + b) * EMBED + h * HDIM + gsrc * 8;
            gload_lds16(srcK, &Kl[buf][w * 16 + p * 8][0]);
            const ushort_t* srcV =
                VT + ((size_t)(bh * 64 + row)) * KPAD + kbase + gsrc * 8;
            gload_lds16(srcV, &Vt[buf][w * 16 + p * 8][0]);
        }
    };

    stage(0, 0);
    __syncthreads();
    int cur = 0;

    for (int kt = 0; kt < 21; ++kt) {
        const int k0 = kt * 64;

        // --- masks for this tile
        uint2 pw = *(const uint2*)&pm_p[b * MROWSTRIDE + 2 * kt];
        uint2 aw[4];
        #pragma unroll
        for (int r = 0; r < 4; ++r) {
            int q = q0 + w * 16 + l4 * 4 + r;
            if (q >= Q_) q = Q_ - 1;
            aw[r] = *(const uint2*)&am_p[(size_t)q * MROWSTRIDE + 2 * kt];
        }

        // --- prefetch next tile into other buffer
        if (kt < 20) stage(k0 + 64, cur ^ 1);

        // --- QK^T: 2-term (Qhi + Qlo) x K
        f32x4 S[4];
        __builtin_amdgcn_s_setprio(1);
        #pragma unroll
        for (int c = 0; c < 4; ++c) {
            f32x4 acc = (f32x4){0.f, 0.f, 0.f, 0.f};
            int krow = c * 16 + l15;
            #pragma unroll
            for (int dh = 0; dh < 2; ++dh) {
                int gr = ((dh * 4 + l4) ^ (krow & 7)) * 8;
                bf16x8 Bh = *(const bf16x8*)&Kl[cur][krow][gr];
                acc = MFMA16(Qhi[dh], Bh, acc);
                acc = MFMA16(Qlo[dh], Bh, acc);
            }
            S[c] = acc;
        }
        __builtin_amdgcn_s_setprio(0);

        // --- masks + online softmax (rows q=l4*4+r, cols c*16+l15)
        float p_[4][4];   // [c][r]
        float al[4];
        #pragma unroll
        for (int r = 0; r < 4; ++r) {
            unsigned m0 = aw[r].x | pw.x;
            unsigned m1 = aw[r].y | pw.y;
            float t = -INFINITY;
            #pragma unroll
            for (int c = 0; c < 4; ++c) {
                int kg = k0 + c * 16 + l15;
                unsigned half = (c & 2) ? m1 : m0;
                float s = S[c][r];
                if ((half >> (((c & 1) << 4) + l15)) & 1) s = NEG_INF_F;
                if (kg >= KV_) s = -INFINITY;
                p_[c][r] = s;
                t = fmaxf(t, s);
            }
            #pragma unroll
            for (int msk = 1; msk < 16; msk <<= 1) t = fmaxf(t, __shfl_xor(t, msk, 64));
            float mn = fmaxf(m[r], t);
            al[r] = __expf(m[r] - mn);
            m[r] = mn;
            float ps = 0.f;
            #pragma unroll
            for (int c = 0; c < 4; ++c) {
                float pe = __expf(p_[c][r] - mn);
                p_[c][r] = pe;
                ps += pe;
            }
            #pragma unroll
            for (int msk = 1; msk < 16; msk <<= 1) ps += __shfl_xor(ps, msk, 64);
            ssum[r] = ssum[r] * al[r] + ps;
        }

        // --- P -> per-wave LDS (bf16)
        #pragma unroll
        for (int r = 0; r < 4; ++r) {
            int qr = l4 * 4 + r;
            #pragma unroll
            for (int c = 0; c < 4; ++c)
                Pb[w][qr][c * 16 + l15] = f2bf(p_[c][r]);
        }

        // --- O rescale
        #pragma unroll
        for (int dg = 0; dg < 4; ++dg)
            #pragma unroll
            for (int r = 0; r < 4; ++r) O[dg][r] *= al[r];

        // --- PA fragments
        bf16x8 PA[2];
        #pragma unroll
        for (int kh = 0; kh < 2; ++kh)
            PA[kh] = *(const bf16x8*)&Pb[w][l15][kh * 32 + l4 * 8];

        // --- PV: conflict-free swizzled Vt reads (b128), 8 MFMA
        __builtin_amdgcn_s_setprio(1);
        #pragma unroll
        for (int kh = 0; kh < 2; ++kh)
            #pragma unroll
            for (int dg = 0; dg < 4; ++dg) {
                int vcb = ((kh * 4 + l4) ^ (l15 & 7)) << 3;
                bf16x8 VB = *(const bf16x8*)&Vt[cur][dg * 16 + l15][vcb];
                O[dg] = MFMA16(PA[kh], VB, O[dg]);
            }
        __builtin_amdgcn_s_setprio(0);

        __syncthreads();
        cur ^= 1;
    }

    // --- epilogue: write ctx hi/lo planes
    #pragma unroll
    for (int r = 0; r < 4; ++r) {
        int qd = q0 + w * 16 + l4 * 4 + r;
        if (qd >= Q_) continue;
        float inv = 1.f / ssum[r];
        #pragma unroll
        for (int dg = 0; dg < 4; ++dg) {
            float v = O[dg][r] * inv;
            size_t off = ((size_t)qd * B_ + b) * EMBED + h * HDIM + dg * 16 + l15;
            unsigned short hb = f2bf(v);
            Chi_p[off] = hb;
            Clo_p[off] = f2bf(v - bf2f(hb));
        }
    }
}

// ---------------------------------------------------------------------------
extern "C" void kernel_launch(void* const* d_in, const int* in_sizes, int n_in,
                              void* d_out, int out_size, void* d_ws, size_t ws_size,
                              hipStream_t stream) {
    const float* utter = (const float*)d_in[0];
    const float* rctx  = (const float*)d_in[1];
    const float* summ  = (const float*)d_in[2];
    const float* mem   = (const float*)d_in[3];
    const int* amask   = (const int*)d_in[4];
    const int* pmask   = (const int*)d_in[5];
    const float* Wq  = (const float*)d_in[6];
    const float* bq  = (const float*)d_in[7];
    const float* Wkv = (const float*)d_in[8];
    const float* bkv = (const float*)d_in[9];
    const float* Wo  = (const float*)d_in[10];
    const float* bo  = (const float*)d_in[11];

    const size_t UT_OFF = 0;
    const size_t RC_OFF = 8388608;
    const size_t SM_OFF = 10485760;
    const size_t MM_OFF = 10747904;
    const size_t SRC_N  = 11001856;
    const size_t WQ_OFF = 0, WKV_OFF = 262144, WO_OFF = 786432;
    const size_t W_N = 1048576;
    const size_t KVPLANE = (size_t)KVPAD_ROWS * B_ * EMBED;   // 11,010,048
    // VT: 128 bh-groups x 64 d x KPAD k = 8192*1344 = 11,010,048 == KVPLANE

    ushort_t* p = (ushort_t*)d_ws;
    ushort_t* SRC_hi = p;                p += SRC_N;
    ushort_t* SRC_lo = p;                p += SRC_N;
    ushort_t* Wp_hi  = p;                p += W_N;
    ushort_t* Wp_lo  = p;                p += W_N;
    ushort_t* Qhi_p  = p;                p += (size_t)QROWS * EMBED;
    ushort_t* Qlo_p  = p;                p += (size_t)QROWS * EMBED;
    ushort_t* Khi_p  = p;                p += KVPLANE;
    ushort_t* VT_p   = p;                p += KVPLANE;
    ushort_t* Vp     = p;                p += KVPLANE;
    ushort_t* Chi_p  = p;                p += (size_t)QROWS * EMBED;
    ushort_t* Clo_p  = p;                p += (size_t)QROWS * EMBED;
    unsigned* am_p   = (unsigned*)p;     p += (size_t)2 * KVPAD_ROWS * MROWSTRIDE;
    unsigned* pm_p   = (unsigned*)p;     p += (size_t)2 * B_ * MROWSTRIDE;

    float* out0 = (float*)d_out;
    float* out1 = out0 + (size_t)OUT0_ROWS * EMBED;

    dim3 blk(256);

    auto cv = [&](const float* s, ushort_t* hi, ushort_t* lo, size_t n) {
        int n8 = (int)(n / 8);
        cvt_hilo<<<dim3((n8 + 255) / 256), blk, 0, stream>>>(s, hi, lo, n8);
    };
    cv(utter, SRC_hi + UT_OFF, SRC_lo + UT_OFF, (size_t)U_ * B_ * EMBED);
    cv(rctx,  SRC_hi + RC_OFF, SRC_lo + RC_OFF, (size_t)R_ * B_ * EMBED);
    cv(summ,  SRC_hi + SM_OFF, SRC_lo + SM_OFF, (size_t)S_ * B_ * EMBED);
    cv(mem,   SRC_hi + MM_OFF, SRC_lo + MM_OFF, (size_t)M_ * B_ * EMBED);
    cv(Wq,  Wp_hi + WQ_OFF,  Wp_lo + WQ_OFF,  (size_t)EMBED * EMBED);
    cv(Wkv, Wp_hi + WKV_OFF, Wp_lo + WKV_OFF, (size_t)2 * EMBED * EMBED);
    cv(Wo,  Wp_hi + WO_OFF,  Wp_lo + WO_OFF,  (size_t)EMBED * EMBED);

    // pack masks
    {
        int total = Q_ * MROWSTRIDE + B_ * MROWSTRIDE;
        pack_aux<<<dim3((total + 255) / 256), blk, 0, stream>>>(
            amask, pmask, am_p, pm_p);
    }

    gemm_mfma<0><<<dim3(QROWS / 128, EMBED / 128), blk, 0, stream>>>(
        SRC_hi, SRC_lo, Wp_hi + WQ_OFF, Wp_lo + WQ_OFF, bq, 0.125f,
        R_ * B_, (R_ + U_) * B_, QROWS, RC_OFF, UT_OFF, SM_OFF,
        Qhi_p, Qlo_p, nullptr);

    gemm_mfma<1><<<dim3((KVROWS + 127) / 128, (2 * EMBED) / 128), blk, 0, stream>>>(
        SRC_hi, SRC_lo, Wp_hi + WKV_OFF, Wp_lo + WKV_OFF, bkv, 1.0f,
        M_ * B_, (M_ + R_) * B_, KVROWS, MM_OFF, RC_OFF, UT_OFF,
        Khi_p, nullptr, Vp);

    vtrans<<<dim3(21, 128), blk, 0, stream>>>(Vp, VT_p);

    attn_mfma<<<dim3((Q_ + 63) / 64, B_ * NHEAD), blk, 0, stream>>>(
        Qhi_p, Qlo_p, Khi_p, VT_p, am_p, pm_p, Chi_p, Clo_p);

    gemm_mfma<2><<<dim3(QROWS / 128, EMBED / 128), blk, 0, stream>>>(
        Chi_p, Clo_p, Wp_hi + WO_OFF, Wp_lo + WO_OFF, bo, 1.0f,
        QROWS, QROWS, QROWS, 0, 0, 0,
        out0, out1, nullptr);
}